// Round 1
// baseline (575.910 us; speedup 1.0000x reference)
//
#include <hip/hip_runtime.h>
#include <hip/hip_bf16.h>

// BiGAT: 2-layer GAT forward.
// N=50000 nodes, IN_CH=128, HID=32, HEADS=8, NCLS=16, E=800000 (+N self loops).
// Strategy: build CSR-by-dst once (count/scan/scatter), fp32 tiled GEMMs,
// online-softmax gather aggregation (one block per node).

#define IN_CH 128
#define HIDC  256   // HEADS*HID
#define NCLS  16
#define NEG_SLOPE 0.2f

// ---------------- CSR construction ----------------

__global__ void count_kernel(const int* __restrict__ ei, int* __restrict__ counts,
                             int E, int Etot) {
    int e = blockIdx.x * blockDim.x + threadIdx.x;
    if (e >= Etot) return;
    int dst = (e < E) ? ei[E + e] : (e - E);
    atomicAdd(&counts[dst], 1);
}

__global__ __launch_bounds__(1024) void scan_kernel(const int* __restrict__ counts,
                                                    int* __restrict__ row_start, int n) {
    __shared__ int wsum[16];
    __shared__ int carry_s;
    int tid = threadIdx.x;
    int lane = tid & 63, wid = tid >> 6;
    if (tid == 0) carry_s = 0;
    __syncthreads();
    for (int base = 0; base < n; base += 1024) {
        int i = base + tid;
        int v = (i < n) ? counts[i] : 0;
        int x = v;
        #pragma unroll
        for (int off = 1; off < 64; off <<= 1) {
            int t = __shfl_up(x, off);
            if (lane >= off) x += t;
        }
        if (lane == 63) wsum[wid] = x;
        __syncthreads();
        if (wid == 0 && lane < 16) {
            int w = wsum[lane];
            #pragma unroll
            for (int off = 1; off < 16; off <<= 1) {
                int t = __shfl_up(w, off);
                if (lane >= off) w += t;
            }
            wsum[lane] = w;  // inclusive over waves
        }
        __syncthreads();
        int wave_excl = (wid > 0) ? wsum[wid - 1] : 0;
        if (i < n) row_start[i] = carry_s + wave_excl + (x - v);
        __syncthreads();
        if (tid == 0) carry_s += wsum[15];
        __syncthreads();
    }
    if (tid == 0) row_start[n] = carry_s;
}

__global__ void scatter_kernel(const int* __restrict__ ei, const int* __restrict__ row_start,
                               int* __restrict__ cursor, int* __restrict__ col,
                               int E, int Etot) {
    int e = blockIdx.x * blockDim.x + threadIdx.x;
    if (e >= Etot) return;
    int src, dst;
    if (e < E) { src = ei[e]; dst = ei[E + e]; }
    else       { src = e - E; dst = e - E; }
    int pos = row_start[dst] + atomicAdd(&cursor[dst], 1);
    col[pos] = src;
}

// ---------------- GEMM1: H[M x 256] = x[M x 128] * W1[128 x 256] ----------------

__global__ __launch_bounds__(256) void gemm1_kernel(const float* __restrict__ A,
                                                    const float* __restrict__ B,
                                                    float* __restrict__ C, int M) {
    __shared__ float As[64][65];
    __shared__ float Bs[64][68];
    int tid = threadIdx.x;
    int tx = tid & 15, ty = tid >> 4;
    int row0 = blockIdx.x * 64, col0 = blockIdx.y * 64;
    float acc[4][4] = {};
    for (int k0 = 0; k0 < 128; k0 += 64) {
        #pragma unroll
        for (int it = 0; it < 16; ++it) {
            int idx = tid + it * 256;
            int r = idx >> 6, k = idx & 63;
            int gr = row0 + r;
            As[r][k] = (gr < M) ? A[gr * IN_CH + k0 + k] : 0.f;
        }
        #pragma unroll
        for (int it = 0; it < 16; ++it) {
            int idx = tid + it * 256;
            int k = idx >> 6, c = idx & 63;
            Bs[k][c] = B[(k0 + k) * HIDC + col0 + c];
        }
        __syncthreads();
        #pragma unroll 8
        for (int k = 0; k < 64; ++k) {
            float a[4];
            #pragma unroll
            for (int i = 0; i < 4; ++i) a[i] = As[ty * 4 + i][k];
            float4 b = *reinterpret_cast<const float4*>(&Bs[k][tx * 4]);
            #pragma unroll
            for (int i = 0; i < 4; ++i) {
                acc[i][0] += a[i] * b.x;
                acc[i][1] += a[i] * b.y;
                acc[i][2] += a[i] * b.z;
                acc[i][3] += a[i] * b.w;
            }
        }
        __syncthreads();
    }
    #pragma unroll
    for (int i = 0; i < 4; ++i) {
        int gr = row0 + ty * 4 + i;
        if (gr < M) {
            float4 v = make_float4(acc[i][0], acc[i][1], acc[i][2], acc[i][3]);
            *reinterpret_cast<float4*>(&C[gr * HIDC + col0 + tx * 4]) = v;
        }
    }
}

// ---------------- Attention dots, layer 1: [N,8] ----------------

__global__ void att1_kernel(const float* __restrict__ H, const float* __restrict__ a_src,
                            const float* __restrict__ a_dst,
                            float* __restrict__ ES, float* __restrict__ ED, int N) {
    int idx = blockIdx.x * blockDim.x + threadIdx.x;  // n*8 + h
    if (idx >= N * 8) return;
    int h = idx & 7;
    const float4* hp = reinterpret_cast<const float4*>(H + (size_t)idx * 32);
    const float4* asp = reinterpret_cast<const float4*>(a_src + h * 32);
    const float4* adp = reinterpret_cast<const float4*>(a_dst + h * 32);
    float es = 0.f, ed = 0.f;
    #pragma unroll
    for (int i = 0; i < 8; ++i) {
        float4 hv = hp[i], av = asp[i], dv = adp[i];
        es += hv.x * av.x + hv.y * av.y + hv.z * av.z + hv.w * av.w;
        ed += hv.x * dv.x + hv.y * dv.y + hv.z * dv.z + hv.w * dv.w;
    }
    ES[idx] = es;
    ED[idx] = ed;
}

// ---------------- Layer-1 aggregation (online softmax), +bias +ELU ----------------

__global__ __launch_bounds__(256) void agg1_kernel(const float* __restrict__ H,
                                                   const float* __restrict__ ES,
                                                   const float* __restrict__ ED,
                                                   const int* __restrict__ row_start,
                                                   const int* __restrict__ col,
                                                   const float* __restrict__ b1,
                                                   float* __restrict__ h1) {
    int n = blockIdx.x;
    int tid = threadIdx.x;
    int h = tid >> 5;
    int s0 = row_start[n], s1 = row_start[n + 1];
    float ed = ED[n * 8 + h];
    float m = -3.0e38f, s = 0.f, acc = 0.f;
    for (int i = s0; i < s1; ++i) {
        int src = col[i];
        float e = ES[src * 8 + h] + ed;
        e = e > 0.f ? e : NEG_SLOPE * e;
        if (e > m) {
            float sc = __expf(m - e);
            s *= sc; acc *= sc; m = e;
        }
        float p = __expf(e - m);
        s += p;
        acc += p * H[(size_t)src * HIDC + tid];
    }
    float v = acc / s + b1[tid];
    h1[(size_t)n * HIDC + tid] = v > 0.f ? v : expm1f(v);
}

// ---------------- GEMM2: H2[N x 16] = h1[N x 256] * W2[256 x 16] ----------------

__global__ __launch_bounds__(256) void gemm2_kernel(const float* __restrict__ X,
                                                    const float* __restrict__ W,
                                                    float* __restrict__ Y, int N) {
    __shared__ float Ws[16][260];  // transposed: Ws[col][k]
    __shared__ float Xs[16][260];
    int tid = threadIdx.x;
    #pragma unroll
    for (int it = 0; it < 16; ++it) {
        int idx = tid + it * 256;
        int k = idx >> 4, c = idx & 15;
        Ws[c][k] = W[k * NCLS + c];
    }
    int row0 = blockIdx.x * 16;
    #pragma unroll
    for (int it = 0; it < 16; ++it) {
        int idx = tid + it * 256;
        int r = idx >> 8, k = idx & 255;
        int gr = row0 + r;
        Xs[r][k] = (gr < N) ? X[(size_t)gr * HIDC + k] : 0.f;
    }
    __syncthreads();
    int r = tid >> 4, c = tid & 15;
    float acc = 0.f;
    #pragma unroll 8
    for (int k = 0; k < 256; k += 4) {
        float4 xv = *reinterpret_cast<const float4*>(&Xs[r][k]);
        float4 wv = *reinterpret_cast<const float4*>(&Ws[c][k]);
        acc += xv.x * wv.x + xv.y * wv.y + xv.z * wv.z + xv.w * wv.w;
    }
    if (row0 + r < N) Y[(size_t)(row0 + r) * NCLS + c] = acc;
}

// ---------------- Attention dots, layer 2: [N] ----------------

__global__ void att2_kernel(const float* __restrict__ H2, const float* __restrict__ a_src,
                            const float* __restrict__ a_dst,
                            float* __restrict__ ES, float* __restrict__ ED, int N) {
    int n = blockIdx.x * blockDim.x + threadIdx.x;
    if (n >= N) return;
    const float4* hp = reinterpret_cast<const float4*>(H2 + (size_t)n * NCLS);
    float es = 0.f, ed = 0.f;
    #pragma unroll
    for (int i = 0; i < 4; ++i) {
        float4 hv = hp[i];
        float4 av = reinterpret_cast<const float4*>(a_src)[i];
        float4 dv = reinterpret_cast<const float4*>(a_dst)[i];
        es += hv.x * av.x + hv.y * av.y + hv.z * av.z + hv.w * av.w;
        ed += hv.x * dv.x + hv.y * dv.y + hv.z * dv.z + hv.w * dv.w;
    }
    ES[n] = es;
    ED[n] = ed;
}

// ---------------- Layer-2 aggregation + bias ----------------

__global__ __launch_bounds__(256) void agg2_kernel(const float* __restrict__ H2,
                                                   const float* __restrict__ ES,
                                                   const float* __restrict__ ED,
                                                   const int* __restrict__ row_start,
                                                   const int* __restrict__ col,
                                                   const float* __restrict__ b2,
                                                   float* __restrict__ out, int N) {
    int g = blockIdx.x * 16 + (threadIdx.x >> 4);
    int c = threadIdx.x & 15;
    if (g >= N) return;
    int s0 = row_start[g], s1 = row_start[g + 1];
    float ed = ED[g];
    float m = -3.0e38f, s = 0.f, acc = 0.f;
    for (int i = s0; i < s1; ++i) {
        int src = col[i];
        float e = ES[src] + ed;
        e = e > 0.f ? e : NEG_SLOPE * e;
        if (e > m) {
            float sc = __expf(m - e);
            s *= sc; acc *= sc; m = e;
        }
        float p = __expf(e - m);
        s += p;
        acc += p * H2[(size_t)src * NCLS + c];
    }
    out[(size_t)g * NCLS + c] = acc / s + b2[c];
}

// ---------------- launch ----------------

extern "C" void kernel_launch(void* const* d_in, const int* in_sizes, int n_in,
                              void* d_out, int out_size, void* d_ws, size_t ws_size,
                              hipStream_t stream) {
    const float* x   = (const float*)d_in[0];
    const int*   ei  = (const int*)d_in[1];
    const float* W1  = (const float*)d_in[2];
    const float* as1 = (const float*)d_in[3];
    const float* ad1 = (const float*)d_in[4];
    const float* b1  = (const float*)d_in[5];
    const float* W2  = (const float*)d_in[6];
    const float* as2 = (const float*)d_in[7];
    const float* ad2 = (const float*)d_in[8];
    const float* b2  = (const float*)d_in[9];
    float* out = (float*)d_out;

    int N = in_sizes[0] / IN_CH;
    int E = in_sizes[1] / 2;
    int Etot = E + N;

    char* ws = (char*)d_ws;
    size_t off = 0;
    auto alloc = [&](size_t bytes) -> void* {
        void* p = ws + off;
        off += (bytes + 255) & ~(size_t)255;
        return p;
    };
    float* H   = (float*)alloc((size_t)N * HIDC * 4);
    float* h1  = (float*)alloc((size_t)N * HIDC * 4);
    float* H2  = (float*)alloc((size_t)N * NCLS * 4);
    float* ES1 = (float*)alloc((size_t)N * 8 * 4);
    float* ED1 = (float*)alloc((size_t)N * 8 * 4);
    float* ES2 = (float*)alloc((size_t)N * 4);
    float* ED2 = (float*)alloc((size_t)N * 4);
    int* counts = (int*)alloc((size_t)N * 2 * 4);  // counts + cursor, adjacent for one memset
    int* cursor = counts + N;
    int* row_start = (int*)alloc((size_t)(N + 1) * 4);
    int* col = (int*)alloc((size_t)Etot * 4);

    hipMemsetAsync(counts, 0, (size_t)N * 2 * 4, stream);

    int eb = (Etot + 255) / 256;
    count_kernel<<<eb, 256, 0, stream>>>(ei, counts, E, Etot);
    scan_kernel<<<1, 1024, 0, stream>>>(counts, row_start, N);
    scatter_kernel<<<eb, 256, 0, stream>>>(ei, row_start, cursor, col, E, Etot);

    dim3 g1((N + 63) / 64, 4);
    gemm1_kernel<<<g1, 256, 0, stream>>>(x, W1, H, N);
    att1_kernel<<<(N * 8 + 255) / 256, 256, 0, stream>>>(H, as1, ad1, ES1, ED1, N);
    agg1_kernel<<<N, 256, 0, stream>>>(H, ES1, ED1, row_start, col, b1, h1);
    gemm2_kernel<<<(N + 15) / 16, 256, 0, stream>>>(h1, W2, H2, N);
    att2_kernel<<<(N + 255) / 256, 256, 0, stream>>>(H2, as2, ad2, ES2, ED2, N);
    agg2_kernel<<<(N + 15) / 16, 256, 0, stream>>>(H2, ES2, ED2, row_start, col, b2, out, N);
}

// Round 2
// 493.457 us; speedup vs baseline: 1.1671x; 1.1671x over previous
//
#include <hip/hip_runtime.h>
#include <hip/hip_bf16.h>

// BiGAT: 2-layer GAT forward.
// N=50000 nodes, IN_CH=128, HID=32, HEADS=8, NCLS=16, E=800000 (+N self loops).
// R2: agg kernels restructured to 1 wave/node (was 4 waves/node) with float4
// channels + 2-way edge-unrolled online softmax -> 4x fewer VALU wave-ops.

#define IN_CH 128
#define HIDC  256   // HEADS*HID
#define NCLS  16
#define NEG_SLOPE 0.2f

// ---------------- CSR construction ----------------

__global__ void count_kernel(const int* __restrict__ ei, int* __restrict__ counts,
                             int E, int Etot) {
    int e = blockIdx.x * blockDim.x + threadIdx.x;
    if (e >= Etot) return;
    int dst = (e < E) ? ei[E + e] : (e - E);
    atomicAdd(&counts[dst], 1);
}

__global__ __launch_bounds__(1024) void scan_kernel(const int* __restrict__ counts,
                                                    int* __restrict__ row_start, int n) {
    __shared__ int wsum[16];
    __shared__ int carry_s;
    int tid = threadIdx.x;
    int lane = tid & 63, wid = tid >> 6;
    if (tid == 0) carry_s = 0;
    __syncthreads();
    for (int base = 0; base < n; base += 1024) {
        int i = base + tid;
        int v = (i < n) ? counts[i] : 0;
        int x = v;
        #pragma unroll
        for (int off = 1; off < 64; off <<= 1) {
            int t = __shfl_up(x, off);
            if (lane >= off) x += t;
        }
        if (lane == 63) wsum[wid] = x;
        __syncthreads();
        if (wid == 0 && lane < 16) {
            int w = wsum[lane];
            #pragma unroll
            for (int off = 1; off < 16; off <<= 1) {
                int t = __shfl_up(w, off);
                if (lane >= off) w += t;
            }
            wsum[lane] = w;  // inclusive over waves
        }
        __syncthreads();
        int wave_excl = (wid > 0) ? wsum[wid - 1] : 0;
        if (i < n) row_start[i] = carry_s + wave_excl + (x - v);
        __syncthreads();
        if (tid == 0) carry_s += wsum[15];
        __syncthreads();
    }
    if (tid == 0) row_start[n] = carry_s;
}

__global__ void scatter_kernel(const int* __restrict__ ei, const int* __restrict__ row_start,
                               int* __restrict__ cursor, int* __restrict__ col,
                               int E, int Etot) {
    int e = blockIdx.x * blockDim.x + threadIdx.x;
    if (e >= Etot) return;
    int src, dst;
    if (e < E) { src = ei[e]; dst = ei[E + e]; }
    else       { src = e - E; dst = e - E; }
    int pos = row_start[dst] + atomicAdd(&cursor[dst], 1);
    col[pos] = src;
}

// ---------------- GEMM1: H[M x 256] = x[M x 128] * W1[128 x 256] ----------------

__global__ __launch_bounds__(256) void gemm1_kernel(const float* __restrict__ A,
                                                    const float* __restrict__ B,
                                                    float* __restrict__ C, int M) {
    __shared__ float As[64][65];
    __shared__ float Bs[64][68];
    int tid = threadIdx.x;
    int tx = tid & 15, ty = tid >> 4;
    int row0 = blockIdx.x * 64, col0 = blockIdx.y * 64;
    float acc[4][4] = {};
    for (int k0 = 0; k0 < 128; k0 += 64) {
        #pragma unroll
        for (int it = 0; it < 16; ++it) {
            int idx = tid + it * 256;
            int r = idx >> 6, k = idx & 63;
            int gr = row0 + r;
            As[r][k] = (gr < M) ? A[gr * IN_CH + k0 + k] : 0.f;
        }
        #pragma unroll
        for (int it = 0; it < 16; ++it) {
            int idx = tid + it * 256;
            int k = idx >> 6, c = idx & 63;
            Bs[k][c] = B[(k0 + k) * HIDC + col0 + c];
        }
        __syncthreads();
        #pragma unroll 8
        for (int k = 0; k < 64; ++k) {
            float a[4];
            #pragma unroll
            for (int i = 0; i < 4; ++i) a[i] = As[ty * 4 + i][k];
            float4 b = *reinterpret_cast<const float4*>(&Bs[k][tx * 4]);
            #pragma unroll
            for (int i = 0; i < 4; ++i) {
                acc[i][0] += a[i] * b.x;
                acc[i][1] += a[i] * b.y;
                acc[i][2] += a[i] * b.z;
                acc[i][3] += a[i] * b.w;
            }
        }
        __syncthreads();
    }
    #pragma unroll
    for (int i = 0; i < 4; ++i) {
        int gr = row0 + ty * 4 + i;
        if (gr < M) {
            float4 v = make_float4(acc[i][0], acc[i][1], acc[i][2], acc[i][3]);
            *reinterpret_cast<float4*>(&C[gr * HIDC + col0 + tx * 4]) = v;
        }
    }
}

// ---------------- Attention dots, layer 1: [N,8] ----------------

__global__ void att1_kernel(const float* __restrict__ H, const float* __restrict__ a_src,
                            const float* __restrict__ a_dst,
                            float* __restrict__ ES, float* __restrict__ ED, int N) {
    int idx = blockIdx.x * blockDim.x + threadIdx.x;  // n*8 + h
    if (idx >= N * 8) return;
    int h = idx & 7;
    const float4* hp = reinterpret_cast<const float4*>(H + (size_t)idx * 32);
    const float4* asp = reinterpret_cast<const float4*>(a_src + h * 32);
    const float4* adp = reinterpret_cast<const float4*>(a_dst + h * 32);
    float es = 0.f, ed = 0.f;
    #pragma unroll
    for (int i = 0; i < 8; ++i) {
        float4 hv = hp[i], av = asp[i], dv = adp[i];
        es += hv.x * av.x + hv.y * av.y + hv.z * av.z + hv.w * av.w;
        ed += hv.x * dv.x + hv.y * dv.y + hv.z * dv.z + hv.w * dv.w;
    }
    ES[idx] = es;
    ED[idx] = ed;
}

// ---------------- Layer-1 aggregation (online softmax), +bias +ELU ----------------
// One 64-lane wave per node. lane = h*8 + cg ; handles head h, channels cg*4..+3.
// 2-way edge unroll: two independent online-softmax states, flash-merged at end.

__global__ __launch_bounds__(64) void agg1_kernel(const float* __restrict__ H,
                                                  const float* __restrict__ ES,
                                                  const float* __restrict__ ED,
                                                  const int* __restrict__ row_start,
                                                  const int* __restrict__ col,
                                                  const float* __restrict__ b1,
                                                  float* __restrict__ h1) {
    int n = blockIdx.x;
    int lane = threadIdx.x;
    int h = lane >> 3;
    int s0 = row_start[n], s1 = row_start[n + 1];
    float ed = ED[n * 8 + h];

    float mA = -3.0e38f, sA = 0.f;
    float mB = -3.0e38f, sB = 0.f;
    float4 accA = make_float4(0.f, 0.f, 0.f, 0.f);
    float4 accB = make_float4(0.f, 0.f, 0.f, 0.f);

    int i = s0;
    for (; i + 1 < s1; i += 2) {
        int srcA = col[i];
        int srcB = col[i + 1];
        float eA = ES[srcA * 8 + h] + ed;
        float eB = ES[srcB * 8 + h] + ed;
        float4 hvA = *reinterpret_cast<const float4*>(&H[(size_t)srcA * HIDC + lane * 4]);
        float4 hvB = *reinterpret_cast<const float4*>(&H[(size_t)srcB * HIDC + lane * 4]);
        eA = eA > 0.f ? eA : NEG_SLOPE * eA;
        eB = eB > 0.f ? eB : NEG_SLOPE * eB;
        if (eA > mA) {
            float sc = __expf(mA - eA);
            sA *= sc; accA.x *= sc; accA.y *= sc; accA.z *= sc; accA.w *= sc;
            mA = eA;
        }
        float pA = __expf(eA - mA);
        sA += pA;
        accA.x += pA * hvA.x; accA.y += pA * hvA.y;
        accA.z += pA * hvA.z; accA.w += pA * hvA.w;
        if (eB > mB) {
            float sc = __expf(mB - eB);
            sB *= sc; accB.x *= sc; accB.y *= sc; accB.z *= sc; accB.w *= sc;
            mB = eB;
        }
        float pB = __expf(eB - mB);
        sB += pB;
        accB.x += pB * hvB.x; accB.y += pB * hvB.y;
        accB.z += pB * hvB.z; accB.w += pB * hvB.w;
    }
    if (i < s1) {
        int src = col[i];
        float e = ES[src * 8 + h] + ed;
        float4 hv = *reinterpret_cast<const float4*>(&H[(size_t)src * HIDC + lane * 4]);
        e = e > 0.f ? e : NEG_SLOPE * e;
        if (e > mA) {
            float sc = __expf(mA - e);
            sA *= sc; accA.x *= sc; accA.y *= sc; accA.z *= sc; accA.w *= sc;
            mA = e;
        }
        float p = __expf(e - mA);
        sA += p;
        accA.x += p * hv.x; accA.y += p * hv.y;
        accA.z += p * hv.z; accA.w += p * hv.w;
    }
    // flash-merge chains A and B
    float mn = fmaxf(mA, mB);
    float scA = __expf(mA - mn), scB = __expf(mB - mn);
    float s = sA * scA + sB * scB;
    float4 acc;
    acc.x = accA.x * scA + accB.x * scB;
    acc.y = accA.y * scA + accB.y * scB;
    acc.z = accA.z * scA + accB.z * scB;
    acc.w = accA.w * scA + accB.w * scB;

    float inv = 1.0f / s;
    const float4 bv = *reinterpret_cast<const float4*>(&b1[lane * 4]);
    float4 v;
    v.x = acc.x * inv + bv.x;
    v.y = acc.y * inv + bv.y;
    v.z = acc.z * inv + bv.z;
    v.w = acc.w * inv + bv.w;
    v.x = v.x > 0.f ? v.x : expm1f(v.x);
    v.y = v.y > 0.f ? v.y : expm1f(v.y);
    v.z = v.z > 0.f ? v.z : expm1f(v.z);
    v.w = v.w > 0.f ? v.w : expm1f(v.w);
    *reinterpret_cast<float4*>(&h1[(size_t)n * HIDC + lane * 4]) = v;
}

// ---------------- GEMM2: H2[N x 16] = h1[N x 256] * W2[256 x 16] ----------------

__global__ __launch_bounds__(256) void gemm2_kernel(const float* __restrict__ X,
                                                    const float* __restrict__ W,
                                                    float* __restrict__ Y, int N) {
    __shared__ float Ws[16][260];  // transposed: Ws[col][k]
    __shared__ float Xs[16][260];
    int tid = threadIdx.x;
    #pragma unroll
    for (int it = 0; it < 16; ++it) {
        int idx = tid + it * 256;
        int k = idx >> 4, c = idx & 15;
        Ws[c][k] = W[k * NCLS + c];
    }
    int row0 = blockIdx.x * 16;
    #pragma unroll
    for (int it = 0; it < 16; ++it) {
        int idx = tid + it * 256;
        int r = idx >> 8, k = idx & 255;
        int gr = row0 + r;
        Xs[r][k] = (gr < N) ? X[(size_t)gr * HIDC + k] : 0.f;
    }
    __syncthreads();
    int r = tid >> 4, c = tid & 15;
    float acc = 0.f;
    #pragma unroll 8
    for (int k = 0; k < 256; k += 4) {
        float4 xv = *reinterpret_cast<const float4*>(&Xs[r][k]);
        float4 wv = *reinterpret_cast<const float4*>(&Ws[c][k]);
        acc += xv.x * wv.x + xv.y * wv.y + xv.z * wv.z + xv.w * wv.w;
    }
    if (row0 + r < N) Y[(size_t)(row0 + r) * NCLS + c] = acc;
}

// ---------------- Attention dots, layer 2: [N] ----------------

__global__ void att2_kernel(const float* __restrict__ H2, const float* __restrict__ a_src,
                            const float* __restrict__ a_dst,
                            float* __restrict__ ES, float* __restrict__ ED, int N) {
    int n = blockIdx.x * blockDim.x + threadIdx.x;
    if (n >= N) return;
    const float4* hp = reinterpret_cast<const float4*>(H2 + (size_t)n * NCLS);
    float es = 0.f, ed = 0.f;
    #pragma unroll
    for (int i = 0; i < 4; ++i) {
        float4 hv = hp[i];
        float4 av = reinterpret_cast<const float4*>(a_src)[i];
        float4 dv = reinterpret_cast<const float4*>(a_dst)[i];
        es += hv.x * av.x + hv.y * av.y + hv.z * av.z + hv.w * av.w;
        ed += hv.x * dv.x + hv.y * dv.y + hv.z * dv.z + hv.w * dv.w;
    }
    ES[n] = es;
    ED[n] = ed;
}

// ---------------- Layer-2 aggregation + bias ----------------
// One wave per node. lane = ep*16 + c : 4 edges in flight (ep), 16 classes (c).
// Per-ep online softmax states flash-merged across ep groups via shfl_xor.

__global__ __launch_bounds__(64) void agg2_kernel(const float* __restrict__ H2,
                                                  const float* __restrict__ ES,
                                                  const float* __restrict__ ED,
                                                  const int* __restrict__ row_start,
                                                  const int* __restrict__ col,
                                                  const float* __restrict__ b2,
                                                  float* __restrict__ out, int N) {
    int g = blockIdx.x;
    int lane = threadIdx.x;
    int ep = lane >> 4, c = lane & 15;
    int s0 = row_start[g], s1 = row_start[g + 1];
    float ed = ED[g];
    float m = -3.0e38f, s = 0.f, acc = 0.f;
    for (int i = s0 + ep; i < s1; i += 4) {
        int src = col[i];
        float e = ES[src] + ed;
        e = e > 0.f ? e : NEG_SLOPE * e;
        if (e > m) {
            float sc = __expf(m - e);
            s *= sc; acc *= sc; m = e;
        }
        float p = __expf(e - m);
        s += p;
        acc += p * H2[(size_t)src * NCLS + c];
    }
    // flash-merge across the 4 ep groups (lanes differing in bits 4,5)
    #pragma unroll
    for (int off = 16; off < 64; off <<= 1) {
        float mo = __shfl_xor(m, off);
        float so = __shfl_xor(s, off);
        float ao = __shfl_xor(acc, off);
        float mn = fmaxf(m, mo);
        float sc1 = __expf(m - mn), sc2 = __expf(mo - mn);
        s = s * sc1 + so * sc2;
        acc = acc * sc1 + ao * sc2;
        m = mn;
    }
    if (lane < 16) out[(size_t)g * NCLS + c] = acc / s + b2[c];
}

// ---------------- launch ----------------

extern "C" void kernel_launch(void* const* d_in, const int* in_sizes, int n_in,
                              void* d_out, int out_size, void* d_ws, size_t ws_size,
                              hipStream_t stream) {
    const float* x   = (const float*)d_in[0];
    const int*   ei  = (const int*)d_in[1];
    const float* W1  = (const float*)d_in[2];
    const float* as1 = (const float*)d_in[3];
    const float* ad1 = (const float*)d_in[4];
    const float* b1  = (const float*)d_in[5];
    const float* W2  = (const float*)d_in[6];
    const float* as2 = (const float*)d_in[7];
    const float* ad2 = (const float*)d_in[8];
    const float* b2  = (const float*)d_in[9];
    float* out = (float*)d_out;

    int N = in_sizes[0] / IN_CH;
    int E = in_sizes[1] / 2;
    int Etot = E + N;

    char* ws = (char*)d_ws;
    size_t off = 0;
    auto alloc = [&](size_t bytes) -> void* {
        void* p = ws + off;
        off += (bytes + 255) & ~(size_t)255;
        return p;
    };
    float* H   = (float*)alloc((size_t)N * HIDC * 4);
    float* h1  = (float*)alloc((size_t)N * HIDC * 4);
    float* H2  = (float*)alloc((size_t)N * NCLS * 4);
    float* ES1 = (float*)alloc((size_t)N * 8 * 4);
    float* ED1 = (float*)alloc((size_t)N * 8 * 4);
    float* ES2 = (float*)alloc((size_t)N * 4);
    float* ED2 = (float*)alloc((size_t)N * 4);
    int* counts = (int*)alloc((size_t)N * 2 * 4);  // counts + cursor, adjacent for one memset
    int* cursor = counts + N;
    int* row_start = (int*)alloc((size_t)(N + 1) * 4);
    int* col = (int*)alloc((size_t)Etot * 4);

    hipMemsetAsync(counts, 0, (size_t)N * 2 * 4, stream);

    int eb = (Etot + 255) / 256;
    count_kernel<<<eb, 256, 0, stream>>>(ei, counts, E, Etot);
    scan_kernel<<<1, 1024, 0, stream>>>(counts, row_start, N);
    scatter_kernel<<<eb, 256, 0, stream>>>(ei, row_start, cursor, col, E, Etot);

    dim3 g1((N + 63) / 64, 4);
    gemm1_kernel<<<g1, 256, 0, stream>>>(x, W1, H, N);
    att1_kernel<<<(N * 8 + 255) / 256, 256, 0, stream>>>(H, as1, ad1, ES1, ED1, N);
    agg1_kernel<<<N, 64, 0, stream>>>(H, ES1, ED1, row_start, col, b1, h1);
    gemm2_kernel<<<(N + 15) / 16, 256, 0, stream>>>(h1, W2, H2, N);
    att2_kernel<<<(N + 255) / 256, 256, 0, stream>>>(H2, as2, ad2, ES2, ED2, N);
    agg2_kernel<<<N, 64, 0, stream>>>(H2, ES2, ED2, row_start, col, b2, out, N);
}

// Round 3
// 443.459 us; speedup vs baseline: 1.2987x; 1.1127x over previous
//
#include <hip/hip_runtime.h>
#include <hip/hip_bf16.h>

// BiGAT: 2-layer GAT forward.
// N=50000 nodes, IN_CH=128, HID=32, HEADS=8, NCLS=16, E=800000 (+N self loops).
// R3: H stored bf16 (halves the 870MB layer-1 gather); agg1 4-way edge unroll
// with hoisted loads + 4 nodes/block for occupancy.

#define IN_CH 128
#define HIDC  256   // HEADS*HID
#define NCLS  16
#define NEG_SLOPE 0.2f

__device__ __forceinline__ unsigned short f2bf(float f) {
    unsigned int u = __float_as_uint(f);
    unsigned int r = (u + 0x7fffu + ((u >> 16) & 1u)) >> 16;
    return (unsigned short)r;
}
__device__ __forceinline__ float bf_lo(unsigned int w) {  // low ushort -> float
    return __uint_as_float(w << 16);
}
__device__ __forceinline__ float bf_hi(unsigned int w) {  // high ushort -> float
    return __uint_as_float(w & 0xffff0000u);
}

// ---------------- CSR construction ----------------

__global__ void count_kernel(const int* __restrict__ ei, int* __restrict__ counts,
                             int E, int Etot) {
    int e = blockIdx.x * blockDim.x + threadIdx.x;
    if (e >= Etot) return;
    int dst = (e < E) ? ei[E + e] : (e - E);
    atomicAdd(&counts[dst], 1);
}

__global__ __launch_bounds__(1024) void scan_kernel(const int* __restrict__ counts,
                                                    int* __restrict__ row_start, int n) {
    __shared__ int wsum[16];
    __shared__ int carry_s;
    int tid = threadIdx.x;
    int lane = tid & 63, wid = tid >> 6;
    if (tid == 0) carry_s = 0;
    __syncthreads();
    for (int base = 0; base < n; base += 1024) {
        int i = base + tid;
        int v = (i < n) ? counts[i] : 0;
        int x = v;
        #pragma unroll
        for (int off = 1; off < 64; off <<= 1) {
            int t = __shfl_up(x, off);
            if (lane >= off) x += t;
        }
        if (lane == 63) wsum[wid] = x;
        __syncthreads();
        if (wid == 0 && lane < 16) {
            int w = wsum[lane];
            #pragma unroll
            for (int off = 1; off < 16; off <<= 1) {
                int t = __shfl_up(w, off);
                if (lane >= off) w += t;
            }
            wsum[lane] = w;  // inclusive over waves
        }
        __syncthreads();
        int wave_excl = (wid > 0) ? wsum[wid - 1] : 0;
        if (i < n) row_start[i] = carry_s + wave_excl + (x - v);
        __syncthreads();
        if (tid == 0) carry_s += wsum[15];
        __syncthreads();
    }
    if (tid == 0) row_start[n] = carry_s;
}

__global__ void scatter_kernel(const int* __restrict__ ei, const int* __restrict__ row_start,
                               int* __restrict__ cursor, int* __restrict__ col,
                               int E, int Etot) {
    int e = blockIdx.x * blockDim.x + threadIdx.x;
    if (e >= Etot) return;
    int src, dst;
    if (e < E) { src = ei[e]; dst = ei[E + e]; }
    else       { src = e - E; dst = e - E; }
    int pos = row_start[dst] + atomicAdd(&cursor[dst], 1);
    col[pos] = src;
}

// ---------------- GEMM1: Hb[M x 256](bf16) = x[M x 128] * W1[128 x 256] ----------------

__global__ __launch_bounds__(256) void gemm1_kernel(const float* __restrict__ A,
                                                    const float* __restrict__ B,
                                                    unsigned short* __restrict__ Hb, int M) {
    __shared__ float As[64][65];
    __shared__ float Bs[64][68];
    int tid = threadIdx.x;
    int tx = tid & 15, ty = tid >> 4;
    int row0 = blockIdx.x * 64, col0 = blockIdx.y * 64;
    float acc[4][4] = {};
    for (int k0 = 0; k0 < 128; k0 += 64) {
        #pragma unroll
        for (int it = 0; it < 16; ++it) {
            int idx = tid + it * 256;
            int r = idx >> 6, k = idx & 63;
            int gr = row0 + r;
            As[r][k] = (gr < M) ? A[gr * IN_CH + k0 + k] : 0.f;
        }
        #pragma unroll
        for (int it = 0; it < 16; ++it) {
            int idx = tid + it * 256;
            int k = idx >> 6, c = idx & 63;
            Bs[k][c] = B[(k0 + k) * HIDC + col0 + c];
        }
        __syncthreads();
        #pragma unroll 8
        for (int k = 0; k < 64; ++k) {
            float a[4];
            #pragma unroll
            for (int i = 0; i < 4; ++i) a[i] = As[ty * 4 + i][k];
            float4 b = *reinterpret_cast<const float4*>(&Bs[k][tx * 4]);
            #pragma unroll
            for (int i = 0; i < 4; ++i) {
                acc[i][0] += a[i] * b.x;
                acc[i][1] += a[i] * b.y;
                acc[i][2] += a[i] * b.z;
                acc[i][3] += a[i] * b.w;
            }
        }
        __syncthreads();
    }
    #pragma unroll
    for (int i = 0; i < 4; ++i) {
        int gr = row0 + ty * 4 + i;
        if (gr < M) {
            uint2 w;
            w.x = (unsigned int)f2bf(acc[i][0]) | ((unsigned int)f2bf(acc[i][1]) << 16);
            w.y = (unsigned int)f2bf(acc[i][2]) | ((unsigned int)f2bf(acc[i][3]) << 16);
            *reinterpret_cast<uint2*>(&Hb[(size_t)gr * HIDC + col0 + tx * 4]) = w;
        }
    }
}

// ---------------- Attention dots, layer 1: [N,8] ----------------

__global__ void att1_kernel(const unsigned short* __restrict__ Hb,
                            const float* __restrict__ a_src, const float* __restrict__ a_dst,
                            float* __restrict__ ES, float* __restrict__ ED, int N) {
    int idx = blockIdx.x * blockDim.x + threadIdx.x;  // n*8 + h
    if (idx >= N * 8) return;
    int h = idx & 7;
    const uint4* hp = reinterpret_cast<const uint4*>(Hb + (size_t)idx * 32);
    float es = 0.f, ed = 0.f;
    #pragma unroll
    for (int i = 0; i < 4; ++i) {
        uint4 v = hp[i];
        unsigned int w[4] = {v.x, v.y, v.z, v.w};
        #pragma unroll
        for (int j = 0; j < 4; ++j) {
            int c = i * 8 + j * 2;
            float f0 = bf_lo(w[j]), f1 = bf_hi(w[j]);
            es += f0 * a_src[h * 32 + c] + f1 * a_src[h * 32 + c + 1];
            ed += f0 * a_dst[h * 32 + c] + f1 * a_dst[h * 32 + c + 1];
        }
    }
    ES[idx] = es;
    ED[idx] = ed;
}

// ---------------- Layer-1 aggregation (online softmax), +bias +ELU ----------------
// 4 nodes per 256-thread block; one wave per node. lane = h*8 + cg.
// 4-way edge unroll, loads hoisted, 4 independent softmax states flash-merged.

__global__ __launch_bounds__(256) void agg1_kernel(const unsigned short* __restrict__ Hb,
                                                   const float* __restrict__ ES,
                                                   const float* __restrict__ ED,
                                                   const int* __restrict__ row_start,
                                                   const int* __restrict__ col,
                                                   const float* __restrict__ b1,
                                                   float* __restrict__ h1, int N) {
    int n = blockIdx.x * 4 + (threadIdx.x >> 6);
    if (n >= N) return;
    int lane = threadIdx.x & 63;
    int h = lane >> 3;
    int s0 = row_start[n], s1 = row_start[n + 1];
    float ed = ED[n * 8 + h];
    const unsigned short* hbase = Hb + lane * 4;

    float m[4] = {-3.0e38f, -3.0e38f, -3.0e38f, -3.0e38f};
    float s[4] = {0.f, 0.f, 0.f, 0.f};
    float4 acc[4] = {};

    int i = s0;
    for (; i + 3 < s1; i += 4) {
        int src[4];
        #pragma unroll
        for (int u = 0; u < 4; ++u) src[u] = col[i + u];
        float e[4];
        uint2 v[4];
        #pragma unroll
        for (int u = 0; u < 4; ++u) {
            e[u] = ES[src[u] * 8 + h];
            v[u] = *reinterpret_cast<const uint2*>(hbase + (size_t)src[u] * HIDC);
        }
        #pragma unroll
        for (int u = 0; u < 4; ++u) {
            float ee = e[u] + ed;
            ee = ee > 0.f ? ee : NEG_SLOPE * ee;
            float mn = fmaxf(m[u], ee);
            float sc = __expf(m[u] - mn);
            float p = __expf(ee - mn);
            m[u] = mn;
            float f0 = bf_lo(v[u].x), f1 = bf_hi(v[u].x);
            float f2 = bf_lo(v[u].y), f3 = bf_hi(v[u].y);
            s[u] = s[u] * sc + p;
            acc[u].x = acc[u].x * sc + p * f0;
            acc[u].y = acc[u].y * sc + p * f1;
            acc[u].z = acc[u].z * sc + p * f2;
            acc[u].w = acc[u].w * sc + p * f3;
        }
    }
    for (; i < s1; ++i) {
        int src = col[i];
        float ee = ES[src * 8 + h] + ed;
        uint2 v = *reinterpret_cast<const uint2*>(hbase + (size_t)src * HIDC);
        ee = ee > 0.f ? ee : NEG_SLOPE * ee;
        float mn = fmaxf(m[0], ee);
        float sc = __expf(m[0] - mn);
        float p = __expf(ee - mn);
        m[0] = mn;
        float f0 = bf_lo(v.x), f1 = bf_hi(v.x);
        float f2 = bf_lo(v.y), f3 = bf_hi(v.y);
        s[0] = s[0] * sc + p;
        acc[0].x = acc[0].x * sc + p * f0;
        acc[0].y = acc[0].y * sc + p * f1;
        acc[0].z = acc[0].z * sc + p * f2;
        acc[0].w = acc[0].w * sc + p * f3;
    }
    // merge states: 1->0, 3->2, 2->0
    #pragma unroll
    for (int step = 0; step < 3; ++step) {
        int a = (step == 0) ? 0 : (step == 1) ? 2 : 0;
        int b = (step == 0) ? 1 : (step == 1) ? 3 : 2;
        float mn = fmaxf(m[a], m[b]);
        float sca = __expf(m[a] - mn), scb = __expf(m[b] - mn);
        s[a] = s[a] * sca + s[b] * scb;
        acc[a].x = acc[a].x * sca + acc[b].x * scb;
        acc[a].y = acc[a].y * sca + acc[b].y * scb;
        acc[a].z = acc[a].z * sca + acc[b].z * scb;
        acc[a].w = acc[a].w * sca + acc[b].w * scb;
        m[a] = mn;
    }

    float inv = 1.0f / s[0];
    const float4 bv = *reinterpret_cast<const float4*>(&b1[lane * 4]);
    float4 o;
    o.x = acc[0].x * inv + bv.x;
    o.y = acc[0].y * inv + bv.y;
    o.z = acc[0].z * inv + bv.z;
    o.w = acc[0].w * inv + bv.w;
    o.x = o.x > 0.f ? o.x : expm1f(o.x);
    o.y = o.y > 0.f ? o.y : expm1f(o.y);
    o.z = o.z > 0.f ? o.z : expm1f(o.z);
    o.w = o.w > 0.f ? o.w : expm1f(o.w);
    *reinterpret_cast<float4*>(&h1[(size_t)n * HIDC + lane * 4]) = o;
}

// ---------------- GEMM2: H2[N x 16] = h1[N x 256] * W2[256 x 16] ----------------

__global__ __launch_bounds__(256) void gemm2_kernel(const float* __restrict__ X,
                                                    const float* __restrict__ W,
                                                    float* __restrict__ Y, int N) {
    __shared__ float Ws[16][260];  // transposed: Ws[col][k]
    __shared__ float Xs[16][260];
    int tid = threadIdx.x;
    #pragma unroll
    for (int it = 0; it < 16; ++it) {
        int idx = tid + it * 256;
        int k = idx >> 4, c = idx & 15;
        Ws[c][k] = W[k * NCLS + c];
    }
    int row0 = blockIdx.x * 16;
    #pragma unroll
    for (int it = 0; it < 16; ++it) {
        int idx = tid + it * 256;
        int r = idx >> 8, k = idx & 255;
        int gr = row0 + r;
        Xs[r][k] = (gr < N) ? X[(size_t)gr * HIDC + k] : 0.f;
    }
    __syncthreads();
    int r = tid >> 4, c = tid & 15;
    float acc = 0.f;
    #pragma unroll 8
    for (int k = 0; k < 256; k += 4) {
        float4 xv = *reinterpret_cast<const float4*>(&Xs[r][k]);
        float4 wv = *reinterpret_cast<const float4*>(&Ws[c][k]);
        acc += xv.x * wv.x + xv.y * wv.y + xv.z * wv.z + xv.w * wv.w;
    }
    if (row0 + r < N) Y[(size_t)(row0 + r) * NCLS + c] = acc;
}

// ---------------- Attention dots, layer 2: [N] ----------------

__global__ void att2_kernel(const float* __restrict__ H2, const float* __restrict__ a_src,
                            const float* __restrict__ a_dst,
                            float* __restrict__ ES, float* __restrict__ ED, int N) {
    int n = blockIdx.x * blockDim.x + threadIdx.x;
    if (n >= N) return;
    const float4* hp = reinterpret_cast<const float4*>(H2 + (size_t)n * NCLS);
    float es = 0.f, ed = 0.f;
    #pragma unroll
    for (int i = 0; i < 4; ++i) {
        float4 hv = hp[i];
        float4 av = reinterpret_cast<const float4*>(a_src)[i];
        float4 dv = reinterpret_cast<const float4*>(a_dst)[i];
        es += hv.x * av.x + hv.y * av.y + hv.z * av.z + hv.w * av.w;
        ed += hv.x * dv.x + hv.y * dv.y + hv.z * dv.z + hv.w * dv.w;
    }
    ES[n] = es;
    ED[n] = ed;
}

// ---------------- Layer-2 aggregation + bias ----------------
// One wave per node. lane = ep*16 + c : 4 edges in flight (ep), 16 classes (c).

__global__ __launch_bounds__(64) void agg2_kernel(const float* __restrict__ H2,
                                                  const float* __restrict__ ES,
                                                  const float* __restrict__ ED,
                                                  const int* __restrict__ row_start,
                                                  const int* __restrict__ col,
                                                  const float* __restrict__ b2,
                                                  float* __restrict__ out, int N) {
    int g = blockIdx.x;
    int lane = threadIdx.x;
    int ep = lane >> 4, c = lane & 15;
    int s0 = row_start[g], s1 = row_start[g + 1];
    float ed = ED[g];
    float m = -3.0e38f, s = 0.f, acc = 0.f;
    for (int i = s0 + ep; i < s1; i += 4) {
        int src = col[i];
        float e = ES[src] + ed;
        e = e > 0.f ? e : NEG_SLOPE * e;
        float mn = fmaxf(m, e);
        float sc = __expf(m - mn);
        float p = __expf(e - mn);
        m = mn;
        s = s * sc + p;
        acc = acc * sc + p * H2[(size_t)src * NCLS + c];
    }
    #pragma unroll
    for (int off = 16; off < 64; off <<= 1) {
        float mo = __shfl_xor(m, off);
        float so = __shfl_xor(s, off);
        float ao = __shfl_xor(acc, off);
        float mn = fmaxf(m, mo);
        float sc1 = __expf(m - mn), sc2 = __expf(mo - mn);
        s = s * sc1 + so * sc2;
        acc = acc * sc1 + ao * sc2;
        m = mn;
    }
    if (lane < 16) out[(size_t)g * NCLS + c] = acc / s + b2[c];
}

// ---------------- launch ----------------

extern "C" void kernel_launch(void* const* d_in, const int* in_sizes, int n_in,
                              void* d_out, int out_size, void* d_ws, size_t ws_size,
                              hipStream_t stream) {
    const float* x   = (const float*)d_in[0];
    const int*   ei  = (const int*)d_in[1];
    const float* W1  = (const float*)d_in[2];
    const float* as1 = (const float*)d_in[3];
    const float* ad1 = (const float*)d_in[4];
    const float* b1  = (const float*)d_in[5];
    const float* W2  = (const float*)d_in[6];
    const float* as2 = (const float*)d_in[7];
    const float* ad2 = (const float*)d_in[8];
    const float* b2  = (const float*)d_in[9];
    float* out = (float*)d_out;

    int N = in_sizes[0] / IN_CH;
    int E = in_sizes[1] / 2;
    int Etot = E + N;

    char* ws = (char*)d_ws;
    size_t off = 0;
    auto alloc = [&](size_t bytes) -> void* {
        void* p = ws + off;
        off += (bytes + 255) & ~(size_t)255;
        return p;
    };
    unsigned short* Hb = (unsigned short*)alloc((size_t)N * HIDC * 2);
    float* h1  = (float*)alloc((size_t)N * HIDC * 4);
    float* H2  = (float*)alloc((size_t)N * NCLS * 4);
    float* ES1 = (float*)alloc((size_t)N * 8 * 4);
    float* ED1 = (float*)alloc((size_t)N * 8 * 4);
    float* ES2 = (float*)alloc((size_t)N * 4);
    float* ED2 = (float*)alloc((size_t)N * 4);
    int* counts = (int*)alloc((size_t)N * 2 * 4);  // counts + cursor
    int* cursor = counts + N;
    int* row_start = (int*)alloc((size_t)(N + 1) * 4);
    int* col = (int*)alloc((size_t)Etot * 4);

    hipMemsetAsync(counts, 0, (size_t)N * 2 * 4, stream);

    int eb = (Etot + 255) / 256;
    count_kernel<<<eb, 256, 0, stream>>>(ei, counts, E, Etot);
    scan_kernel<<<1, 1024, 0, stream>>>(counts, row_start, N);
    scatter_kernel<<<eb, 256, 0, stream>>>(ei, row_start, cursor, col, E, Etot);

    dim3 g1((N + 63) / 64, 4);
    gemm1_kernel<<<g1, 256, 0, stream>>>(x, W1, Hb, N);
    att1_kernel<<<(N * 8 + 255) / 256, 256, 0, stream>>>(Hb, as1, ad1, ES1, ED1, N);
    agg1_kernel<<<(N + 3) / 4, 256, 0, stream>>>(Hb, ES1, ED1, row_start, col, b1, h1, N);
    gemm2_kernel<<<(N + 15) / 16, 256, 0, stream>>>(h1, W2, H2, N);
    att2_kernel<<<(N + 255) / 256, 256, 0, stream>>>(H2, as2, ad2, ES2, ED2, N);
    agg2_kernel<<<N, 64, 0, stream>>>(H2, ES2, ED2, row_start, col, b2, out, N);
}

// Round 5
// 428.977 us; speedup vs baseline: 1.3425x; 1.0338x over previous
//
#include <hip/hip_runtime.h>
#include <hip/hip_bf16.h>

// BiGAT: 2-layer GAT forward.
// N=50000, IN_CH=128, HID=32, HEADS=8, NCLS=16, E=800000 (+N self loops).
// R4 (resubmit after broker timeout): no-max softmax (direct exp: scores O(8),
// no overflow; ratios identical), CSR segments padded to x4 with p=0 dummy
// edges (uniform unroll, uint4 col loads), col stores byte offsets (src*512)
// to kill per-edge address mults.

#define IN_CH 128
#define HIDC  256   // HEADS*HID
#define NCLS  16
#define NEG_SLOPE 0.2f

__device__ __forceinline__ unsigned short f2bf(float f) {
    unsigned int u = __float_as_uint(f);
    unsigned int r = (u + 0x7fffu + ((u >> 16) & 1u)) >> 16;
    return (unsigned short)r;
}
__device__ __forceinline__ float bf_lo(unsigned int w) { return __uint_as_float(w << 16); }
__device__ __forceinline__ float bf_hi(unsigned int w) { return __uint_as_float(w & 0xffff0000u); }

// ---------------- CSR construction ----------------

__global__ void count_kernel(const int* __restrict__ ei, int* __restrict__ counts,
                             int E, int Etot) {
    int e = blockIdx.x * blockDim.x + threadIdx.x;
    if (e >= Etot) return;
    int dst = (e < E) ? ei[E + e] : (e - E);
    atomicAdd(&counts[dst], 1);
}

// exclusive prefix over PADDED counts ((c+3)&~3) -> every segment multiple of 4
__global__ __launch_bounds__(1024) void scan_kernel(const int* __restrict__ counts,
                                                    int* __restrict__ row_start, int n) {
    __shared__ int wsum[16];
    __shared__ int carry_s;
    int tid = threadIdx.x;
    int lane = tid & 63, wid = tid >> 6;
    if (tid == 0) carry_s = 0;
    __syncthreads();
    for (int base = 0; base < n; base += 1024) {
        int i = base + tid;
        int v = (i < n) ? ((counts[i] + 3) & ~3) : 0;
        int x = v;
        #pragma unroll
        for (int off = 1; off < 64; off <<= 1) {
            int t = __shfl_up(x, off);
            if (lane >= off) x += t;
        }
        if (lane == 63) wsum[wid] = x;
        __syncthreads();
        if (wid == 0 && lane < 16) {
            int w = wsum[lane];
            #pragma unroll
            for (int off = 1; off < 16; off <<= 1) {
                int t = __shfl_up(w, off);
                if (lane >= off) w += t;
            }
            wsum[lane] = w;
        }
        __syncthreads();
        int wave_excl = (wid > 0) ? wsum[wid - 1] : 0;
        if (i < n) row_start[i] = carry_s + wave_excl + (x - v);
        __syncthreads();
        if (tid == 0) carry_s += wsum[15];
        __syncthreads();
    }
    if (tid == 0) row_start[n] = carry_s;
}

// fill col with dummy byte-offset, zero dummy Hb/H2 rows, ES sentinels
__global__ void fill_kernel(int* __restrict__ colB, int fill_n, int dummyB,
                            unsigned short* __restrict__ Hb, float* __restrict__ ES1,
                            float* __restrict__ H2, float* __restrict__ ES2, int N) {
    int i = blockIdx.x * blockDim.x + threadIdx.x;
    if (i < fill_n) colB[i] = dummyB;
    if (i < HIDC) Hb[(size_t)N * HIDC + i] = 0;
    if (i < NCLS) H2[(size_t)N * NCLS + i] = 0.f;
    if (i < 8) ES1[(size_t)N * 8 + i] = -3.0e38f;
    if (i == 0) ES2[N] = -3.0e38f;
}

__global__ void scatter_kernel(const int* __restrict__ ei, const int* __restrict__ row_start,
                               int* __restrict__ cursor, int* __restrict__ colB,
                               int E, int Etot) {
    int e = blockIdx.x * blockDim.x + threadIdx.x;
    if (e >= Etot) return;
    int src, dst;
    if (e < E) { src = ei[e]; dst = ei[E + e]; }
    else       { src = e - E; dst = e - E; }
    int pos = row_start[dst] + atomicAdd(&cursor[dst], 1);
    colB[pos] = src * (HIDC * 2);   // byte offset of Hb row
}

// ---------------- GEMM1: Hb[M x 256](bf16) = x[M x 128] * W1[128 x 256] ----------------

__global__ __launch_bounds__(256) void gemm1_kernel(const float* __restrict__ A,
                                                    const float* __restrict__ B,
                                                    unsigned short* __restrict__ Hb, int M) {
    __shared__ float As[64][65];
    __shared__ float Bs[64][68];
    int tid = threadIdx.x;
    int tx = tid & 15, ty = tid >> 4;
    int row0 = blockIdx.x * 64, col0 = blockIdx.y * 64;
    float acc[4][4] = {};
    for (int k0 = 0; k0 < 128; k0 += 64) {
        #pragma unroll
        for (int it = 0; it < 16; ++it) {
            int idx = tid + it * 256;
            int r = idx >> 6, k = idx & 63;
            int gr = row0 + r;
            As[r][k] = (gr < M) ? A[gr * IN_CH + k0 + k] : 0.f;
        }
        #pragma unroll
        for (int it = 0; it < 16; ++it) {
            int idx = tid + it * 256;
            int k = idx >> 6, c = idx & 63;
            Bs[k][c] = B[(k0 + k) * HIDC + col0 + c];
        }
        __syncthreads();
        #pragma unroll 8
        for (int k = 0; k < 64; ++k) {
            float a[4];
            #pragma unroll
            for (int i = 0; i < 4; ++i) a[i] = As[ty * 4 + i][k];
            float4 b = *reinterpret_cast<const float4*>(&Bs[k][tx * 4]);
            #pragma unroll
            for (int i = 0; i < 4; ++i) {
                acc[i][0] += a[i] * b.x;
                acc[i][1] += a[i] * b.y;
                acc[i][2] += a[i] * b.z;
                acc[i][3] += a[i] * b.w;
            }
        }
        __syncthreads();
    }
    #pragma unroll
    for (int i = 0; i < 4; ++i) {
        int gr = row0 + ty * 4 + i;
        if (gr < M) {
            uint2 w;
            w.x = (unsigned int)f2bf(acc[i][0]) | ((unsigned int)f2bf(acc[i][1]) << 16);
            w.y = (unsigned int)f2bf(acc[i][2]) | ((unsigned int)f2bf(acc[i][3]) << 16);
            *reinterpret_cast<uint2*>(&Hb[(size_t)gr * HIDC + col0 + tx * 4]) = w;
        }
    }
}

// ---------------- Attention dots, layer 1: [N,8] ----------------

__global__ void att1_kernel(const unsigned short* __restrict__ Hb,
                            const float* __restrict__ a_src, const float* __restrict__ a_dst,
                            float* __restrict__ ES, float* __restrict__ ED, int N) {
    int idx = blockIdx.x * blockDim.x + threadIdx.x;  // n*8 + h
    if (idx >= N * 8) return;
    int h = idx & 7;
    const uint4* hp = reinterpret_cast<const uint4*>(Hb + (size_t)idx * 32);
    float es = 0.f, ed = 0.f;
    #pragma unroll
    for (int i = 0; i < 4; ++i) {
        uint4 v = hp[i];
        unsigned int w[4] = {v.x, v.y, v.z, v.w};
        #pragma unroll
        for (int j = 0; j < 4; ++j) {
            int c = i * 8 + j * 2;
            float f0 = bf_lo(w[j]), f1 = bf_hi(w[j]);
            es += f0 * a_src[h * 32 + c] + f1 * a_src[h * 32 + c + 1];
            ed += f0 * a_dst[h * 32 + c] + f1 * a_dst[h * 32 + c + 1];
        }
    }
    ES[idx] = es;
    ED[idx] = ed;
}

// ---------------- Layer-1 aggregation (direct-exp softmax), +bias +ELU ----------------
// 4 nodes / 256-thread block; one wave per node. lane = h*8 + cg.
// Segments padded to x4; dummy edges have ES=-3e38 -> p=0 (Hb dummy row zeroed).

__global__ __launch_bounds__(256) void agg1_kernel(const unsigned short* __restrict__ Hb,
                                                   const float* __restrict__ ES,
                                                   const float* __restrict__ ED,
                                                   const int* __restrict__ row_start,
                                                   const int* __restrict__ colB,
                                                   const float* __restrict__ b1,
                                                   float* __restrict__ h1, int N) {
    int n = blockIdx.x * 4 + (threadIdx.x >> 6);
    if (n >= N) return;
    int lane = threadIdx.x & 63;
    int h = lane >> 3;
    unsigned int hoff = h << 2;       // byte offset into ES row (src*32 | h*4)
    unsigned int lane8 = lane << 3;   // byte offset into Hb row (lane*4 elems * 2B)
    int s0 = row_start[n], s1 = row_start[n + 1];
    float ed = ED[n * 8 + h];
    const char* ESb = (const char*)ES;
    const char* Hbb = (const char*)Hb;

    float s = 0.f;
    float4 acc = make_float4(0.f, 0.f, 0.f, 0.f);

    for (int i = s0; i < s1; i += 4) {
        uint4 cb = *reinterpret_cast<const uint4*>(&colB[i]);
        float e0 = *(const float*)(ESb + ((cb.x >> 4) | hoff));
        float e1 = *(const float*)(ESb + ((cb.y >> 4) | hoff));
        float e2 = *(const float*)(ESb + ((cb.z >> 4) | hoff));
        float e3 = *(const float*)(ESb + ((cb.w >> 4) | hoff));
        uint2 v0 = *(const uint2*)(Hbb + (cb.x + lane8));
        uint2 v1 = *(const uint2*)(Hbb + (cb.y + lane8));
        uint2 v2 = *(const uint2*)(Hbb + (cb.z + lane8));
        uint2 v3 = *(const uint2*)(Hbb + (cb.w + lane8));
        e0 += ed; e1 += ed; e2 += ed; e3 += ed;
        e0 = fmaxf(e0, NEG_SLOPE * e0);
        e1 = fmaxf(e1, NEG_SLOPE * e1);
        e2 = fmaxf(e2, NEG_SLOPE * e2);
        e3 = fmaxf(e3, NEG_SLOPE * e3);
        float p0 = __expf(e0), p1 = __expf(e1), p2 = __expf(e2), p3 = __expf(e3);
        s += (p0 + p1) + (p2 + p3);
        acc.x = fmaf(p0, bf_lo(v0.x), acc.x);
        acc.y = fmaf(p0, bf_hi(v0.x), acc.y);
        acc.z = fmaf(p0, bf_lo(v0.y), acc.z);
        acc.w = fmaf(p0, bf_hi(v0.y), acc.w);
        acc.x = fmaf(p1, bf_lo(v1.x), acc.x);
        acc.y = fmaf(p1, bf_hi(v1.x), acc.y);
        acc.z = fmaf(p1, bf_lo(v1.y), acc.z);
        acc.w = fmaf(p1, bf_hi(v1.y), acc.w);
        acc.x = fmaf(p2, bf_lo(v2.x), acc.x);
        acc.y = fmaf(p2, bf_hi(v2.x), acc.y);
        acc.z = fmaf(p2, bf_lo(v2.y), acc.z);
        acc.w = fmaf(p2, bf_hi(v2.y), acc.w);
        acc.x = fmaf(p3, bf_lo(v3.x), acc.x);
        acc.y = fmaf(p3, bf_hi(v3.x), acc.y);
        acc.z = fmaf(p3, bf_lo(v3.y), acc.z);
        acc.w = fmaf(p3, bf_hi(v3.y), acc.w);
    }

    float inv = 1.0f / s;
    const float4 bv = *reinterpret_cast<const float4*>(&b1[lane * 4]);
    float4 o;
    o.x = acc.x * inv + bv.x;
    o.y = acc.y * inv + bv.y;
    o.z = acc.z * inv + bv.z;
    o.w = acc.w * inv + bv.w;
    o.x = o.x > 0.f ? o.x : expm1f(o.x);
    o.y = o.y > 0.f ? o.y : expm1f(o.y);
    o.z = o.z > 0.f ? o.z : expm1f(o.z);
    o.w = o.w > 0.f ? o.w : expm1f(o.w);
    *reinterpret_cast<float4*>(&h1[(size_t)n * HIDC + lane * 4]) = o;
}

// ---------------- GEMM2: H2[N x 16] = h1[N x 256] * W2[256 x 16] ----------------

__global__ __launch_bounds__(256) void gemm2_kernel(const float* __restrict__ X,
                                                    const float* __restrict__ W,
                                                    float* __restrict__ Y, int N) {
    __shared__ float Ws[16][260];
    __shared__ float Xs[16][260];
    int tid = threadIdx.x;
    #pragma unroll
    for (int it = 0; it < 16; ++it) {
        int idx = tid + it * 256;
        int k = idx >> 4, c = idx & 15;
        Ws[c][k] = W[k * NCLS + c];
    }
    int row0 = blockIdx.x * 16;
    #pragma unroll
    for (int it = 0; it < 16; ++it) {
        int idx = tid + it * 256;
        int r = idx >> 8, k = idx & 255;
        int gr = row0 + r;
        Xs[r][k] = (gr < N) ? X[(size_t)gr * HIDC + k] : 0.f;
    }
    __syncthreads();
    int r = tid >> 4, c = tid & 15;
    float acc = 0.f;
    #pragma unroll 8
    for (int k = 0; k < 256; k += 4) {
        float4 xv = *reinterpret_cast<const float4*>(&Xs[r][k]);
        float4 wv = *reinterpret_cast<const float4*>(&Ws[c][k]);
        acc += xv.x * wv.x + xv.y * wv.y + xv.z * wv.z + xv.w * wv.w;
    }
    if (row0 + r < N) Y[(size_t)(row0 + r) * NCLS + c] = acc;
}

// ---------------- Attention dots, layer 2: [N] ----------------

__global__ void att2_kernel(const float* __restrict__ H2, const float* __restrict__ a_src,
                            const float* __restrict__ a_dst,
                            float* __restrict__ ES, float* __restrict__ ED, int N) {
    int n = blockIdx.x * blockDim.x + threadIdx.x;
    if (n >= N) return;
    const float4* hp = reinterpret_cast<const float4*>(H2 + (size_t)n * NCLS);
    float es = 0.f, ed = 0.f;
    #pragma unroll
    for (int i = 0; i < 4; ++i) {
        float4 hv = hp[i];
        float4 av = reinterpret_cast<const float4*>(a_src)[i];
        float4 dv = reinterpret_cast<const float4*>(a_dst)[i];
        es += hv.x * av.x + hv.y * av.y + hv.z * av.z + hv.w * av.w;
        ed += hv.x * dv.x + hv.y * dv.y + hv.z * dv.z + hv.w * dv.w;
    }
    ES[n] = es;
    ED[n] = ed;
}

// ---------------- Layer-2 aggregation + bias ----------------
// One wave per node. lane = ep*16 + c : 4 edges in flight, 16 classes.
// Direct exp -> plain sum merge across ep groups.

__global__ __launch_bounds__(64) void agg2_kernel(const float* __restrict__ H2,
                                                  const float* __restrict__ ES,
                                                  const float* __restrict__ ED,
                                                  const int* __restrict__ row_start,
                                                  const int* __restrict__ colB,
                                                  const float* __restrict__ b2,
                                                  float* __restrict__ out, int N) {
    int g = blockIdx.x;
    int lane = threadIdx.x;
    int ep = lane >> 4;
    unsigned int c4 = (lane & 15) << 2;   // byte offset within H2 row
    int s0 = row_start[g], s1 = row_start[g + 1];
    float ed = ED[g];
    const char* ESb = (const char*)ES;
    const char* H2b = (const char*)H2;
    float s = 0.f, acc = 0.f;
    for (int i = s0 + ep; i < s1; i += 4) {
        unsigned int cb = (unsigned int)colB[i];
        float e = *(const float*)(ESb + (cb >> 7));
        float hv = *(const float*)(H2b + ((cb >> 3) | c4));
        e += ed;
        e = fmaxf(e, NEG_SLOPE * e);
        float p = __expf(e);
        s += p;
        acc = fmaf(p, hv, acc);
    }
    s += __shfl_xor(s, 16);
    s += __shfl_xor(s, 32);
    acc += __shfl_xor(acc, 16);
    acc += __shfl_xor(acc, 32);
    if (lane < 16) out[(size_t)g * NCLS + lane] = acc / s + b2[lane];
}

// ---------------- launch ----------------

extern "C" void kernel_launch(void* const* d_in, const int* in_sizes, int n_in,
                              void* d_out, int out_size, void* d_ws, size_t ws_size,
                              hipStream_t stream) {
    const float* x   = (const float*)d_in[0];
    const int*   ei  = (const int*)d_in[1];
    const float* W1  = (const float*)d_in[2];
    const float* as1 = (const float*)d_in[3];
    const float* ad1 = (const float*)d_in[4];
    const float* b1  = (const float*)d_in[5];
    const float* W2  = (const float*)d_in[6];
    const float* as2 = (const float*)d_in[7];
    const float* ad2 = (const float*)d_in[8];
    const float* b2  = (const float*)d_in[9];
    float* out = (float*)d_out;

    int N = in_sizes[0] / IN_CH;
    int E = in_sizes[1] / 2;
    int Etot = E + N;
    int fill_n = E + 4 * N;   // upper bound on padded CSR size

    char* ws = (char*)d_ws;
    size_t off = 0;
    auto alloc = [&](size_t bytes) -> void* {
        void* p = ws + off;
        off += (bytes + 255) & ~(size_t)255;
        return p;
    };
    unsigned short* Hb = (unsigned short*)alloc((size_t)(N + 1) * HIDC * 2);
    float* h1  = (float*)alloc((size_t)N * HIDC * 4);
    float* H2  = (float*)alloc((size_t)(N + 1) * NCLS * 4);
    float* ES1 = (float*)alloc((size_t)(N + 1) * 8 * 4);
    float* ED1 = (float*)alloc((size_t)N * 8 * 4);
    float* ES2 = (float*)alloc((size_t)(N + 1) * 4);
    float* ED2 = (float*)alloc((size_t)N * 4);
    int* counts = (int*)alloc((size_t)N * 2 * 4);
    int* cursor = counts + N;
    int* row_start = (int*)alloc((size_t)(N + 1) * 4);
    int* colB = (int*)alloc((size_t)fill_n * 4);

    hipMemsetAsync(counts, 0, (size_t)N * 2 * 4, stream);

    int eb = (Etot + 255) / 256;
    count_kernel<<<eb, 256, 0, stream>>>(ei, counts, E, Etot);
    scan_kernel<<<1, 1024, 0, stream>>>(counts, row_start, N);
    fill_kernel<<<(fill_n + 255) / 256, 256, 0, stream>>>(colB, fill_n, N * HIDC * 2,
                                                          Hb, ES1, H2, ES2, N);
    scatter_kernel<<<eb, 256, 0, stream>>>(ei, row_start, cursor, colB, E, Etot);

    dim3 g1((N + 63) / 64, 4);
    gemm1_kernel<<<g1, 256, 0, stream>>>(x, W1, Hb, N);
    att1_kernel<<<(N * 8 + 255) / 256, 256, 0, stream>>>(Hb, as1, ad1, ES1, ED1, N);
    agg1_kernel<<<(N + 3) / 4, 256, 0, stream>>>(Hb, ES1, ED1, row_start, colB, b1, h1, N);
    gemm2_kernel<<<(N + 15) / 16, 256, 0, stream>>>(h1, W2, H2, N);
    att2_kernel<<<(N + 255) / 256, 256, 0, stream>>>(H2, as2, ad2, ES2, ED2, N);
    agg2_kernel<<<N, 64, 0, stream>>>(H2, ES2, ED2, row_start, colB, b2, out, N);
}

// Round 8
// 383.415 us; speedup vs baseline: 1.5021x; 1.1188x over previous
//
#include <hip/hip_runtime.h>
#include <hip/hip_bf16.h>

// BiGAT: 2-layer GAT forward.
// N=50000, IN_CH=128, HID=32, HEADS=8, NCLS=16, E=800000 (+N self loops).
// R7 (resubmit after broker timeout): fix R6's B-staging offset bug
// (hf*2 -> hf*4 uint4s): each half-thread must source 32 bf16 at element
// hf*32. Rest identical to R6 (MFMA gemm1, 4-elem/thread scan, direct-exp agg).

#define IN_CH 128
#define HIDC  256   // HEADS*HID
#define NCLS  16
#define NEG_SLOPE 0.2f

typedef short bf16x8 __attribute__((ext_vector_type(8)));
typedef float f32x4 __attribute__((ext_vector_type(4)));

__device__ __forceinline__ unsigned int f2bf(float f) {
    unsigned int u = __float_as_uint(f);
    return (u + 0x7fffu + ((u >> 16) & 1u)) >> 16;
}
__device__ __forceinline__ float bf_lo(unsigned int w) { return __uint_as_float(w << 16); }
__device__ __forceinline__ float bf_hi(unsigned int w) { return __uint_as_float(w & 0xffff0000u); }

// ---------------- CSR construction ----------------

__global__ void count_kernel(const int* __restrict__ ei, int* __restrict__ counts,
                             int E, int Etot) {
    int e = blockIdx.x * blockDim.x + threadIdx.x;
    if (e >= Etot) return;
    int dst = (e < E) ? ei[E + e] : (e - E);
    atomicAdd(&counts[dst], 1);
}

// exclusive prefix over PADDED counts ((c+3)&~3); 4 elems/thread via int4
__global__ __launch_bounds__(1024) void scan_kernel(const int* __restrict__ counts,
                                                    int* __restrict__ row_start, int n) {
    __shared__ int wsum[16];
    __shared__ int carry_s;
    int tid = threadIdx.x;
    int lane = tid & 63, wid = tid >> 6;
    if (tid == 0) carry_s = 0;
    __syncthreads();
    for (int base = 0; base < n; base += 4096) {
        int i = base + tid * 4;
        int4 c;
        if (i + 3 < n) {
            c = *reinterpret_cast<const int4*>(counts + i);
        } else {
            c.x = (i     < n) ? counts[i]     : 0;
            c.y = (i + 1 < n) ? counts[i + 1] : 0;
            c.z = (i + 2 < n) ? counts[i + 2] : 0;
            c.w = (i + 3 < n) ? counts[i + 3] : 0;
        }
        c.x = (c.x + 3) & ~3; c.y = (c.y + 3) & ~3;
        c.z = (c.z + 3) & ~3; c.w = (c.w + 3) & ~3;
        int tsum = c.x + c.y + c.z + c.w;
        int x = tsum;
        #pragma unroll
        for (int off = 1; off < 64; off <<= 1) {
            int t = __shfl_up(x, off);
            if (lane >= off) x += t;
        }
        if (lane == 63) wsum[wid] = x;
        __syncthreads();
        if (wid == 0 && lane < 16) {
            int w = wsum[lane];
            #pragma unroll
            for (int off = 1; off < 16; off <<= 1) {
                int t = __shfl_up(w, off);
                if (lane >= off) w += t;
            }
            wsum[lane] = w;
        }
        __syncthreads();
        int wave_excl = (wid > 0) ? wsum[wid - 1] : 0;
        int excl = carry_s + wave_excl + (x - tsum);
        int4 o;
        o.x = excl;
        o.y = excl + c.x;
        o.z = excl + c.x + c.y;
        o.w = excl + c.x + c.y + c.z;
        if (i + 3 < n) {
            *reinterpret_cast<int4*>(row_start + i) = o;
        } else {
            if (i     < n) row_start[i]     = o.x;
            if (i + 1 < n) row_start[i + 1] = o.y;
            if (i + 2 < n) row_start[i + 2] = o.z;
        }
        __syncthreads();
        if (tid == 0) carry_s += wsum[15];
        __syncthreads();
    }
    if (tid == 0) row_start[n] = carry_s;
}

// fill col with dummy byte-offset, zero dummy Hb/H2 rows, ES sentinels
__global__ void fill_kernel(int* __restrict__ colB, int fill_n, int dummyB,
                            unsigned short* __restrict__ Hb, float* __restrict__ ES1,
                            float* __restrict__ H2, float* __restrict__ ES2, int N) {
    int i = blockIdx.x * blockDim.x + threadIdx.x;
    if (i < fill_n) colB[i] = dummyB;
    if (i < HIDC) Hb[(size_t)N * HIDC + i] = 0;
    if (i < NCLS) H2[(size_t)N * NCLS + i] = 0.f;
    if (i < 8) ES1[(size_t)N * 8 + i] = -3.0e38f;
    if (i == 0) ES2[N] = -3.0e38f;
}

__global__ void scatter_kernel(const int* __restrict__ ei, const int* __restrict__ row_start,
                               int* __restrict__ cursor, int* __restrict__ colB,
                               int E, int Etot) {
    int e = blockIdx.x * blockDim.x + threadIdx.x;
    if (e >= Etot) return;
    int src, dst;
    if (e < E) { src = ei[e]; dst = ei[E + e]; }
    else       { src = e - E; dst = e - E; }
    int pos = row_start[dst] + atomicAdd(&cursor[dst], 1);
    colB[pos] = src * (HIDC * 2);   // byte offset of Hb row
}

// ---------------- W1 transpose+cast: W1t[c][k] (bf16) = W1[k][c] ----------------

__global__ void w1t_kernel(const float* __restrict__ W1, unsigned short* __restrict__ W1t) {
    int k = blockIdx.x;       // 0..127
    int c = threadIdx.x;      // 0..255
    W1t[c * IN_CH + k] = (unsigned short)f2bf(W1[k * HIDC + c]);
}

// ---------------- GEMM1 (MFMA bf16): Hb[M x 256] = x[M x 128] * W1 ----------------
// 128x128 tile, 4 waves (2x2 of 64x64), K staged in two 64-halves.
// A/B frags: lane l -> row/col (l&15), k = k0 + (l>>4)*8 + 0..7
// (same k-bijection on both operands -> correct for any HW k-permutation).
// C/D: col = lane&15, row = (lane>>4)*4 + reg  [m89-verified].

#define LDK 72   // 64 k + 8 pad (bf16 elems); row = 144B, 16B aligned

__global__ __launch_bounds__(256) void gemm1_mfma(const float* __restrict__ A,
                                                  const unsigned short* __restrict__ W1t,
                                                  unsigned short* __restrict__ Hb, int M) {
    __shared__ unsigned short As[128 * LDK];
    __shared__ unsigned short Bs[128 * LDK];
    int tid = threadIdx.x;
    int row0 = blockIdx.x * 128, col0 = blockIdx.y * 128;
    int lane = tid & 63, wid = tid >> 6;
    int wr = wid >> 1, wc = wid & 1;
    int la = lane & 15, lg = lane >> 4;
    f32x4 acc[4][4] = {};

    int r = tid >> 1, hf = tid & 1;   // staging: row r (0..127), 32-elem half hf
    int gr = row0 + r;
    bool okA = gr < M;
    const float4* asrc = reinterpret_cast<const float4*>(A + (size_t)(okA ? gr : 0) * IN_CH) + hf * 8;
    const uint4*  bsrc = reinterpret_cast<const uint4*>(W1t + (size_t)(col0 + r) * IN_CH) + hf * 4;
    unsigned short* adst = &As[r * LDK + hf * 32];
    unsigned short* bdst = &Bs[r * LDK + hf * 32];

    #pragma unroll
    for (int kt = 0; kt < 2; ++kt) {
        // stage A half: 32 floats -> bf16
        #pragma unroll
        for (int it = 0; it < 8; ++it) {
            float4 v = okA ? asrc[it] : make_float4(0.f, 0.f, 0.f, 0.f);
            uint2 w;
            w.x = f2bf(v.x) | (f2bf(v.y) << 16);
            w.y = f2bf(v.z) | (f2bf(v.w) << 16);
            *reinterpret_cast<uint2*>(adst + it * 4) = w;
        }
        // stage B half: 32 bf16 (already converted)
        #pragma unroll
        for (int it = 0; it < 4; ++it) {
            uint4 v = bsrc[it];
            *reinterpret_cast<uint4*>(bdst + it * 8) = v;
        }
        asrc += 16;   // advance 64 floats (next k-half)
        bsrc += 8;    // advance 64 bf16
        __syncthreads();
        #pragma unroll
        for (int k0 = 0; k0 < 64; k0 += 32) {
            bf16x8 af[4], bfr[4];
            #pragma unroll
            for (int m = 0; m < 4; ++m)
                af[m] = *reinterpret_cast<const bf16x8*>(&As[(wr * 64 + m * 16 + la) * LDK + k0 + lg * 8]);
            #pragma unroll
            for (int n2 = 0; n2 < 4; ++n2)
                bfr[n2] = *reinterpret_cast<const bf16x8*>(&Bs[(wc * 64 + n2 * 16 + la) * LDK + k0 + lg * 8]);
            #pragma unroll
            for (int m = 0; m < 4; ++m) {
                #pragma unroll
                for (int n2 = 0; n2 < 4; ++n2)
                    acc[m][n2] = __builtin_amdgcn_mfma_f32_16x16x32_bf16(af[m], bfr[n2], acc[m][n2], 0, 0, 0);
            }
        }
        __syncthreads();
    }
    // epilogue: fp32 acc -> bf16 Hb
    #pragma unroll
    for (int m = 0; m < 4; ++m) {
        #pragma unroll
        for (int j = 0; j < 4; ++j) {
            int grow = row0 + wr * 64 + m * 16 + lg * 4 + j;
            if (grow < M) {
                int gcol = col0 + wc * 64 + la;
                #pragma unroll
                for (int n2 = 0; n2 < 4; ++n2)
                    Hb[(size_t)grow * HIDC + gcol + n2 * 16] = (unsigned short)f2bf(acc[m][n2][j]);
            }
        }
    }
}

// ---------------- Attention dots, layer 1: [N,8] ----------------

__global__ void att1_kernel(const unsigned short* __restrict__ Hb,
                            const float* __restrict__ a_src, const float* __restrict__ a_dst,
                            float* __restrict__ ES, float* __restrict__ ED, int N) {
    int idx = blockIdx.x * blockDim.x + threadIdx.x;  // n*8 + h
    if (idx >= N * 8) return;
    int h = idx & 7;
    const uint4* hp = reinterpret_cast<const uint4*>(Hb + (size_t)idx * 32);
    float es = 0.f, ed = 0.f;
    #pragma unroll
    for (int i = 0; i < 4; ++i) {
        uint4 v = hp[i];
        unsigned int w[4] = {v.x, v.y, v.z, v.w};
        #pragma unroll
        for (int j = 0; j < 4; ++j) {
            int c = i * 8 + j * 2;
            float f0 = bf_lo(w[j]), f1 = bf_hi(w[j]);
            es += f0 * a_src[h * 32 + c] + f1 * a_src[h * 32 + c + 1];
            ed += f0 * a_dst[h * 32 + c] + f1 * a_dst[h * 32 + c + 1];
        }
    }
    ES[idx] = es;
    ED[idx] = ed;
}

// ---------------- Layer-1 aggregation (direct-exp softmax), +bias +ELU ----------------

__global__ __launch_bounds__(256) void agg1_kernel(const unsigned short* __restrict__ Hb,
                                                   const float* __restrict__ ES,
                                                   const float* __restrict__ ED,
                                                   const int* __restrict__ row_start,
                                                   const int* __restrict__ colB,
                                                   const float* __restrict__ b1,
                                                   float* __restrict__ h1, int N) {
    int n = blockIdx.x * 4 + (threadIdx.x >> 6);
    if (n >= N) return;
    int lane = threadIdx.x & 63;
    int h = lane >> 3;
    unsigned int hoff = h << 2;
    unsigned int lane8 = lane << 3;
    int s0 = row_start[n], s1 = row_start[n + 1];
    float ed = ED[n * 8 + h];
    const char* ESb = (const char*)ES;
    const char* Hbb = (const char*)Hb;

    float s = 0.f;
    float4 acc = make_float4(0.f, 0.f, 0.f, 0.f);

    for (int i = s0; i < s1; i += 4) {
        uint4 cb = *reinterpret_cast<const uint4*>(&colB[i]);
        float e0 = *(const float*)(ESb + ((cb.x >> 4) | hoff));
        float e1 = *(const float*)(ESb + ((cb.y >> 4) | hoff));
        float e2 = *(const float*)(ESb + ((cb.z >> 4) | hoff));
        float e3 = *(const float*)(ESb + ((cb.w >> 4) | hoff));
        uint2 v0 = *(const uint2*)(Hbb + (cb.x + lane8));
        uint2 v1 = *(const uint2*)(Hbb + (cb.y + lane8));
        uint2 v2 = *(const uint2*)(Hbb + (cb.z + lane8));
        uint2 v3 = *(const uint2*)(Hbb + (cb.w + lane8));
        e0 += ed; e1 += ed; e2 += ed; e3 += ed;
        e0 = fmaxf(e0, NEG_SLOPE * e0);
        e1 = fmaxf(e1, NEG_SLOPE * e1);
        e2 = fmaxf(e2, NEG_SLOPE * e2);
        e3 = fmaxf(e3, NEG_SLOPE * e3);
        float p0 = __expf(e0), p1 = __expf(e1), p2 = __expf(e2), p3 = __expf(e3);
        s += (p0 + p1) + (p2 + p3);
        acc.x = fmaf(p0, bf_lo(v0.x), acc.x);
        acc.y = fmaf(p0, bf_hi(v0.x), acc.y);
        acc.z = fmaf(p0, bf_lo(v0.y), acc.z);
        acc.w = fmaf(p0, bf_hi(v0.y), acc.w);
        acc.x = fmaf(p1, bf_lo(v1.x), acc.x);
        acc.y = fmaf(p1, bf_hi(v1.x), acc.y);
        acc.z = fmaf(p1, bf_lo(v1.y), acc.z);
        acc.w = fmaf(p1, bf_hi(v1.y), acc.w);
        acc.x = fmaf(p2, bf_lo(v2.x), acc.x);
        acc.y = fmaf(p2, bf_hi(v2.x), acc.y);
        acc.z = fmaf(p2, bf_lo(v2.y), acc.z);
        acc.w = fmaf(p2, bf_hi(v2.y), acc.w);
        acc.x = fmaf(p3, bf_lo(v3.x), acc.x);
        acc.y = fmaf(p3, bf_hi(v3.x), acc.y);
        acc.z = fmaf(p3, bf_lo(v3.y), acc.z);
        acc.w = fmaf(p3, bf_hi(v3.y), acc.w);
    }

    float inv = 1.0f / s;
    const float4 bv = *reinterpret_cast<const float4*>(&b1[lane * 4]);
    float4 o;
    o.x = acc.x * inv + bv.x;
    o.y = acc.y * inv + bv.y;
    o.z = acc.z * inv + bv.z;
    o.w = acc.w * inv + bv.w;
    o.x = o.x > 0.f ? o.x : expm1f(o.x);
    o.y = o.y > 0.f ? o.y : expm1f(o.y);
    o.z = o.z > 0.f ? o.z : expm1f(o.z);
    o.w = o.w > 0.f ? o.w : expm1f(o.w);
    *reinterpret_cast<float4*>(&h1[(size_t)n * HIDC + lane * 4]) = o;
}

// ---------------- GEMM2: H2[N x 16] = h1[N x 256] * W2[256 x 16] ----------------

__global__ __launch_bounds__(256) void gemm2_kernel(const float* __restrict__ X,
                                                    const float* __restrict__ W,
                                                    float* __restrict__ Y, int N) {
    __shared__ float Ws[16][260];
    __shared__ float Xs[16][260];
    int tid = threadIdx.x;
    #pragma unroll
    for (int it = 0; it < 16; ++it) {
        int idx = tid + it * 256;
        int k = idx >> 4, c = idx & 15;
        Ws[c][k] = W[k * NCLS + c];
    }
    int row0 = blockIdx.x * 16;
    #pragma unroll
    for (int it = 0; it < 16; ++it) {
        int idx = tid + it * 256;
        int r = idx >> 8, k = idx & 255;
        int gr = row0 + r;
        Xs[r][k] = (gr < N) ? X[(size_t)gr * HIDC + k] : 0.f;
    }
    __syncthreads();
    int r = tid >> 4, c = tid & 15;
    float acc = 0.f;
    #pragma unroll 8
    for (int k = 0; k < 256; k += 4) {
        float4 xv = *reinterpret_cast<const float4*>(&Xs[r][k]);
        float4 wv = *reinterpret_cast<const float4*>(&Ws[c][k]);
        acc += xv.x * wv.x + xv.y * wv.y + xv.z * wv.z + xv.w * wv.w;
    }
    if (row0 + r < N) Y[(size_t)(row0 + r) * NCLS + c] = acc;
}

// ---------------- Attention dots, layer 2: [N] ----------------

__global__ void att2_kernel(const float* __restrict__ H2, const float* __restrict__ a_src,
                            const float* __restrict__ a_dst,
                            float* __restrict__ ES, float* __restrict__ ED, int N) {
    int n = blockIdx.x * blockDim.x + threadIdx.x;
    if (n >= N) return;
    const float4* hp = reinterpret_cast<const float4*>(H2 + (size_t)n * NCLS);
    float es = 0.f, ed = 0.f;
    #pragma unroll
    for (int i = 0; i < 4; ++i) {
        float4 hv = hp[i];
        float4 av = reinterpret_cast<const float4*>(a_src)[i];
        float4 dv = reinterpret_cast<const float4*>(a_dst)[i];
        es += hv.x * av.x + hv.y * av.y + hv.z * av.z + hv.w * av.w;
        ed += hv.x * dv.x + hv.y * dv.y + hv.z * dv.z + hv.w * dv.w;
    }
    ES[n] = es;
    ED[n] = ed;
}

// ---------------- Layer-2 aggregation + bias ----------------

__global__ __launch_bounds__(64) void agg2_kernel(const float* __restrict__ H2,
                                                  const float* __restrict__ ES,
                                                  const float* __restrict__ ED,
                                                  const int* __restrict__ row_start,
                                                  const int* __restrict__ colB,
                                                  const float* __restrict__ b2,
                                                  float* __restrict__ out, int N) {
    int g = blockIdx.x;
    int lane = threadIdx.x;
    int ep = lane >> 4;
    unsigned int c4 = (lane & 15) << 2;
    int s0 = row_start[g], s1 = row_start[g + 1];
    float ed = ED[g];
    const char* ESb = (const char*)ES;
    const char* H2b = (const char*)H2;
    float s = 0.f, acc = 0.f;
    for (int i = s0 + ep; i < s1; i += 4) {
        unsigned int cb = (unsigned int)colB[i];
        float e = *(const float*)(ESb + (cb >> 7));
        float hv = *(const float*)(H2b + ((cb >> 3) | c4));
        e += ed;
        e = fmaxf(e, NEG_SLOPE * e);
        float p = __expf(e);
        s += p;
        acc = fmaf(p, hv, acc);
    }
    s += __shfl_xor(s, 16);
    s += __shfl_xor(s, 32);
    acc += __shfl_xor(acc, 16);
    acc += __shfl_xor(acc, 32);
    if (lane < 16) out[(size_t)g * NCLS + lane] = acc / s + b2[lane];
}

// ---------------- launch ----------------

extern "C" void kernel_launch(void* const* d_in, const int* in_sizes, int n_in,
                              void* d_out, int out_size, void* d_ws, size_t ws_size,
                              hipStream_t stream) {
    const float* x   = (const float*)d_in[0];
    const int*   ei  = (const int*)d_in[1];
    const float* W1  = (const float*)d_in[2];
    const float* as1 = (const float*)d_in[3];
    const float* ad1 = (const float*)d_in[4];
    const float* b1  = (const float*)d_in[5];
    const float* W2  = (const float*)d_in[6];
    const float* as2 = (const float*)d_in[7];
    const float* ad2 = (const float*)d_in[8];
    const float* b2  = (const float*)d_in[9];
    float* out = (float*)d_out;

    int N = in_sizes[0] / IN_CH;
    int E = in_sizes[1] / 2;
    int Etot = E + N;
    int fill_n = E + 4 * N;   // upper bound on padded CSR size

    char* ws = (char*)d_ws;
    size_t off = 0;
    auto alloc = [&](size_t bytes) -> void* {
        void* p = ws + off;
        off += (bytes + 255) & ~(size_t)255;
        return p;
    };
    unsigned short* Hb  = (unsigned short*)alloc((size_t)(N + 1) * HIDC * 2);
    unsigned short* W1t = (unsigned short*)alloc((size_t)HIDC * IN_CH * 2);
    float* h1  = (float*)alloc((size_t)N * HIDC * 4);
    float* H2  = (float*)alloc((size_t)(N + 1) * NCLS * 4);
    float* ES1 = (float*)alloc((size_t)(N + 1) * 8 * 4);
    float* ED1 = (float*)alloc((size_t)N * 8 * 4);
    float* ES2 = (float*)alloc((size_t)(N + 1) * 4);
    float* ED2 = (float*)alloc((size_t)N * 4);
    int* counts = (int*)alloc((size_t)N * 2 * 4);
    int* cursor = counts + N;
    int* row_start = (int*)alloc((size_t)(N + 1) * 4);
    int* colB = (int*)alloc((size_t)fill_n * 4);

    hipMemsetAsync(counts, 0, (size_t)N * 2 * 4, stream);

    int eb = (Etot + 255) / 256;
    count_kernel<<<eb, 256, 0, stream>>>(ei, counts, E, Etot);
    w1t_kernel<<<IN_CH, HIDC, 0, stream>>>(W1, W1t);
    scan_kernel<<<1, 1024, 0, stream>>>(counts, row_start, N);
    fill_kernel<<<(fill_n + 255) / 256, 256, 0, stream>>>(colB, fill_n, N * HIDC * 2,
                                                          Hb, ES1, H2, ES2, N);
    scatter_kernel<<<eb, 256, 0, stream>>>(ei, row_start, cursor, colB, E, Etot);

    dim3 g1((N + 127) / 128, 2);
    gemm1_mfma<<<g1, 256, 0, stream>>>(x, W1t, Hb, N);
    att1_kernel<<<(N * 8 + 255) / 256, 256, 0, stream>>>(Hb, as1, ad1, ES1, ED1, N);
    agg1_kernel<<<(N + 3) / 4, 256, 0, stream>>>(Hb, ES1, ED1, row_start, colB, b1, h1, N);
    gemm2_kernel<<<(N + 15) / 16, 256, 0, stream>>>(h1, W2, H2, N);
    att2_kernel<<<(N + 255) / 256, 256, 0, stream>>>(H2, as2, ad2, ES2, ED2, N);
    agg2_kernel<<<N, 64, 0, stream>>>(H2, ES2, ED2, row_start, colB, b2, out, N);
}

// Round 9
// 354.628 us; speedup vs baseline: 1.6240x; 1.0812x over previous
//
#include <hip/hip_runtime.h>
#include <hip/hip_bf16.h>

// BiGAT: 2-layer GAT forward.
// N=50000, IN_CH=128, HID=32, HEADS=8, NCLS=16, E=800000 (+N self loops).
// R9: agg1 8-deep unroll; att1 fused into gemm1 epilogue (per-block 4 heads,
// shfl-reduced from fp32 acc); att2 fused into gemm2 epilogue; count+fill
// merged; agg2 4 nodes/block.

#define IN_CH 128
#define HIDC  256   // HEADS*HID
#define NCLS  16
#define NEG_SLOPE 0.2f

typedef short bf16x8 __attribute__((ext_vector_type(8)));
typedef float f32x4 __attribute__((ext_vector_type(4)));

__device__ __forceinline__ unsigned int f2bf(float f) {
    unsigned int u = __float_as_uint(f);
    return (u + 0x7fffu + ((u >> 16) & 1u)) >> 16;
}
__device__ __forceinline__ float bf_lo(unsigned int w) { return __uint_as_float(w << 16); }
__device__ __forceinline__ float bf_hi(unsigned int w) { return __uint_as_float(w & 0xffff0000u); }

// ---------------- CSR: count + colB/sentinel fill (merged) ----------------

__global__ void count_fill_kernel(const int* __restrict__ ei, int* __restrict__ counts,
                                  int E, int Etot,
                                  int* __restrict__ colB, int fill_n, int dummyB,
                                  unsigned short* __restrict__ Hb, float* __restrict__ ES1,
                                  float* __restrict__ H2, float* __restrict__ ES2, int N) {
    int i = blockIdx.x * blockDim.x + threadIdx.x;
    if (i < Etot) {
        int dst = (i < E) ? ei[E + i] : (i - E);
        atomicAdd(&counts[dst], 1);
    }
    if (i < fill_n) colB[i] = dummyB;
    if (i < HIDC) Hb[(size_t)N * HIDC + i] = 0;
    if (i < NCLS) H2[(size_t)N * NCLS + i] = 0.f;
    if (i < 8) ES1[(size_t)N * 8 + i] = -3.0e38f;
    if (i == 0) ES2[N] = -3.0e38f;
}

// exclusive prefix over PADDED counts ((c+3)&~3); 4 elems/thread via int4
__global__ __launch_bounds__(1024) void scan_kernel(const int* __restrict__ counts,
                                                    int* __restrict__ row_start, int n) {
    __shared__ int wsum[16];
    __shared__ int carry_s;
    int tid = threadIdx.x;
    int lane = tid & 63, wid = tid >> 6;
    if (tid == 0) carry_s = 0;
    __syncthreads();
    for (int base = 0; base < n; base += 4096) {
        int i = base + tid * 4;
        int4 c;
        if (i + 3 < n) {
            c = *reinterpret_cast<const int4*>(counts + i);
        } else {
            c.x = (i     < n) ? counts[i]     : 0;
            c.y = (i + 1 < n) ? counts[i + 1] : 0;
            c.z = (i + 2 < n) ? counts[i + 2] : 0;
            c.w = (i + 3 < n) ? counts[i + 3] : 0;
        }
        c.x = (c.x + 3) & ~3; c.y = (c.y + 3) & ~3;
        c.z = (c.z + 3) & ~3; c.w = (c.w + 3) & ~3;
        int tsum = c.x + c.y + c.z + c.w;
        int x = tsum;
        #pragma unroll
        for (int off = 1; off < 64; off <<= 1) {
            int t = __shfl_up(x, off);
            if (lane >= off) x += t;
        }
        if (lane == 63) wsum[wid] = x;
        __syncthreads();
        if (wid == 0 && lane < 16) {
            int w = wsum[lane];
            #pragma unroll
            for (int off = 1; off < 16; off <<= 1) {
                int t = __shfl_up(w, off);
                if (lane >= off) w += t;
            }
            wsum[lane] = w;
        }
        __syncthreads();
        int wave_excl = (wid > 0) ? wsum[wid - 1] : 0;
        int excl = carry_s + wave_excl + (x - tsum);
        int4 o;
        o.x = excl;
        o.y = excl + c.x;
        o.z = excl + c.x + c.y;
        o.w = excl + c.x + c.y + c.z;
        if (i + 3 < n) {
            *reinterpret_cast<int4*>(row_start + i) = o;
        } else {
            if (i     < n) row_start[i]     = o.x;
            if (i + 1 < n) row_start[i + 1] = o.y;
            if (i + 2 < n) row_start[i + 2] = o.z;
        }
        __syncthreads();
        if (tid == 0) carry_s += wsum[15];
        __syncthreads();
    }
    if (tid == 0) row_start[n] = carry_s;
}

__global__ void scatter_kernel(const int* __restrict__ ei, const int* __restrict__ row_start,
                               int* __restrict__ cursor, int* __restrict__ colB,
                               int E, int Etot) {
    int e = blockIdx.x * blockDim.x + threadIdx.x;
    if (e >= Etot) return;
    int src, dst;
    if (e < E) { src = ei[e]; dst = ei[E + e]; }
    else       { src = e - E; dst = e - E; }
    int pos = row_start[dst] + atomicAdd(&cursor[dst], 1);
    colB[pos] = src * (HIDC * 2);   // byte offset of Hb row
}

// ---------------- W1 transpose+cast: W1t[c][k] (bf16) = W1[k][c] ----------------

__global__ void w1t_kernel(const float* __restrict__ W1, unsigned short* __restrict__ W1t) {
    int k = blockIdx.x;       // 0..127
    int c = threadIdx.x;      // 0..255
    W1t[c * IN_CH + k] = (unsigned short)f2bf(W1[k * HIDC + c]);
}

// ---------------- GEMM1 (MFMA bf16) + fused att1 ----------------
// 128x128 tile, 4 waves (2x2 of 64x64). Fused epilogue: each block's 128-col
// slice = heads base..base+3; ES1/ED1 via 16-lane shfl reduce of fp32 acc.

#define LDK 72   // 64 k + 8 pad (bf16 elems)

__global__ __launch_bounds__(256) void gemm1_mfma(const float* __restrict__ A,
                                                  const unsigned short* __restrict__ W1t,
                                                  const float* __restrict__ a_src,
                                                  const float* __restrict__ a_dst,
                                                  unsigned short* __restrict__ Hb,
                                                  float* __restrict__ ES,
                                                  float* __restrict__ ED, int M) {
    __shared__ unsigned short As[128 * LDK];
    __shared__ unsigned short Bs[128 * LDK];
    int tid = threadIdx.x;
    int row0 = blockIdx.x * 128, col0 = blockIdx.y * 128;
    int lane = tid & 63, wid = tid >> 6;
    int wr = wid >> 1, wc = wid & 1;
    int la = lane & 15, lg = lane >> 4;
    f32x4 acc[4][4] = {};

    int r = tid >> 1, hf = tid & 1;
    int gr = row0 + r;
    bool okA = gr < M;
    const float4* asrc = reinterpret_cast<const float4*>(A + (size_t)(okA ? gr : 0) * IN_CH) + hf * 8;
    const uint4*  bsrc = reinterpret_cast<const uint4*>(W1t + (size_t)(col0 + r) * IN_CH) + hf * 4;
    unsigned short* adst = &As[r * LDK + hf * 32];
    unsigned short* bdst = &Bs[r * LDK + hf * 32];

    #pragma unroll
    for (int kt = 0; kt < 2; ++kt) {
        #pragma unroll
        for (int it = 0; it < 8; ++it) {
            float4 v = okA ? asrc[it] : make_float4(0.f, 0.f, 0.f, 0.f);
            uint2 w;
            w.x = f2bf(v.x) | (f2bf(v.y) << 16);
            w.y = f2bf(v.z) | (f2bf(v.w) << 16);
            *reinterpret_cast<uint2*>(adst + it * 4) = w;
        }
        #pragma unroll
        for (int it = 0; it < 4; ++it) {
            uint4 v = bsrc[it];
            *reinterpret_cast<uint4*>(bdst + it * 8) = v;
        }
        asrc += 16;
        bsrc += 8;
        __syncthreads();
        #pragma unroll
        for (int k0 = 0; k0 < 64; k0 += 32) {
            bf16x8 af[4], bfr[4];
            #pragma unroll
            for (int m = 0; m < 4; ++m)
                af[m] = *reinterpret_cast<const bf16x8*>(&As[(wr * 64 + m * 16 + la) * LDK + k0 + lg * 8]);
            #pragma unroll
            for (int n2 = 0; n2 < 4; ++n2)
                bfr[n2] = *reinterpret_cast<const bf16x8*>(&Bs[(wc * 64 + n2 * 16 + la) * LDK + k0 + lg * 8]);
            #pragma unroll
            for (int m = 0; m < 4; ++m) {
                #pragma unroll
                for (int n2 = 0; n2 < 4; ++n2)
                    acc[m][n2] = __builtin_amdgcn_mfma_f32_16x16x32_bf16(af[m], bfr[n2], acc[m][n2], 0, 0, 0);
            }
        }
        __syncthreads();
    }

    // Hb write (bf16)
    #pragma unroll
    for (int m = 0; m < 4; ++m) {
        #pragma unroll
        for (int j = 0; j < 4; ++j) {
            int grow = row0 + wr * 64 + m * 16 + lg * 4 + j;
            if (grow < M) {
                int gcol = col0 + wc * 64 + la;
                #pragma unroll
                for (int n2 = 0; n2 < 4; ++n2)
                    Hb[(size_t)grow * HIDC + gcol + n2 * 16] = (unsigned short)f2bf(acc[m][n2][j]);
            }
        }
    }

    // fused att1: this wave covers heads h0,h0+1 (64 cols); ch_local for n2:
    // n2=0 -> la, n2=1 -> la+16 (head h0); n2=2,3 -> head h0+1.
    int h0 = (col0 + wc * 64) >> 5;
    float as00 = a_src[h0 * 32 + la],        as01 = a_src[h0 * 32 + 16 + la];
    float ad00 = a_dst[h0 * 32 + la],        ad01 = a_dst[h0 * 32 + 16 + la];
    float as10 = a_src[(h0 + 1) * 32 + la],  as11 = a_src[(h0 + 1) * 32 + 16 + la];
    float ad10 = a_dst[(h0 + 1) * 32 + la],  ad11 = a_dst[(h0 + 1) * 32 + 16 + la];
    #pragma unroll
    for (int m = 0; m < 4; ++m) {
        #pragma unroll
        for (int j = 0; j < 4; ++j) {
            float v0 = acc[m][0][j], v1 = acc[m][1][j];
            float v2 = acc[m][2][j], v3 = acc[m][3][j];
            float es0 = v0 * as00 + v1 * as01;
            float ed0 = v0 * ad00 + v1 * ad01;
            float es1 = v2 * as10 + v3 * as11;
            float ed1 = v2 * ad10 + v3 * ad11;
            #pragma unroll
            for (int off = 1; off < 16; off <<= 1) {
                es0 += __shfl_xor(es0, off);
                ed0 += __shfl_xor(ed0, off);
                es1 += __shfl_xor(es1, off);
                ed1 += __shfl_xor(ed1, off);
            }
            int grow = row0 + wr * 64 + m * 16 + lg * 4 + j;
            if (la == 0 && grow < M) {
                ES[grow * 8 + h0] = es0;
                ED[grow * 8 + h0] = ed0;
                ES[grow * 8 + h0 + 1] = es1;
                ED[grow * 8 + h0 + 1] = ed1;
            }
        }
    }
}

// ---------------- Layer-1 aggregation: 8-deep unroll ----------------
// 4 nodes / 256-thread block; one wave per node. lane = h*8 + cg.
// Segments padded to x4; dummy edges: ES=-3e38 -> p=0, Hb dummy row zeroed.

#define EDGE4(cbv)                                                              \
    {                                                                           \
        float e0 = *(const float*)(ESb + (((cbv).x >> 4) | hoff));              \
        float e1 = *(const float*)(ESb + (((cbv).y >> 4) | hoff));              \
        float e2 = *(const float*)(ESb + (((cbv).z >> 4) | hoff));              \
        float e3 = *(const float*)(ESb + (((cbv).w >> 4) | hoff));              \
        uint2 v0 = *(const uint2*)(Hbb + ((cbv).x + lane8));                    \
        uint2 v1 = *(const uint2*)(Hbb + ((cbv).y + lane8));                    \
        uint2 v2 = *(const uint2*)(Hbb + ((cbv).z + lane8));                    \
        uint2 v3 = *(const uint2*)(Hbb + ((cbv).w + lane8));                    \
        e0 += ed; e1 += ed; e2 += ed; e3 += ed;                                 \
        e0 = fmaxf(e0, NEG_SLOPE * e0);                                         \
        e1 = fmaxf(e1, NEG_SLOPE * e1);                                         \
        e2 = fmaxf(e2, NEG_SLOPE * e2);                                         \
        e3 = fmaxf(e3, NEG_SLOPE * e3);                                         \
        float p0 = __expf(e0), p1 = __expf(e1), p2 = __expf(e2), p3 = __expf(e3);\
        s += (p0 + p1) + (p2 + p3);                                             \
        acc.x = fmaf(p0, bf_lo(v0.x), acc.x);                                   \
        acc.y = fmaf(p0, bf_hi(v0.x), acc.y);                                   \
        acc.z = fmaf(p0, bf_lo(v0.y), acc.z);                                   \
        acc.w = fmaf(p0, bf_hi(v0.y), acc.w);                                   \
        acc.x = fmaf(p1, bf_lo(v1.x), acc.x);                                   \
        acc.y = fmaf(p1, bf_hi(v1.x), acc.y);                                   \
        acc.z = fmaf(p1, bf_lo(v1.y), acc.z);                                   \
        acc.w = fmaf(p1, bf_hi(v1.y), acc.w);                                   \
        acc.x = fmaf(p2, bf_lo(v2.x), acc.x);                                   \
        acc.y = fmaf(p2, bf_hi(v2.x), acc.y);                                   \
        acc.z = fmaf(p2, bf_lo(v2.y), acc.z);                                   \
        acc.w = fmaf(p2, bf_hi(v2.y), acc.w);                                   \
        acc.x = fmaf(p3, bf_lo(v3.x), acc.x);                                   \
        acc.y = fmaf(p3, bf_hi(v3.x), acc.y);                                   \
        acc.z = fmaf(p3, bf_lo(v3.y), acc.z);                                   \
        acc.w = fmaf(p3, bf_hi(v3.y), acc.w);                                   \
    }

__global__ __launch_bounds__(256) void agg1_kernel(const unsigned short* __restrict__ Hb,
                                                   const float* __restrict__ ES,
                                                   const float* __restrict__ ED,
                                                   const int* __restrict__ row_start,
                                                   const int* __restrict__ colB,
                                                   const float* __restrict__ b1,
                                                   float* __restrict__ h1, int N) {
    int n = blockIdx.x * 4 + (threadIdx.x >> 6);
    if (n >= N) return;
    int lane = threadIdx.x & 63;
    int h = lane >> 3;
    unsigned int hoff = h << 2;
    unsigned int lane8 = lane << 3;
    int s0 = row_start[n], s1 = row_start[n + 1];
    float ed = ED[n * 8 + h];
    const char* ESb = (const char*)ES;
    const char* Hbb = (const char*)Hb;

    float s = 0.f;
    float4 acc = make_float4(0.f, 0.f, 0.f, 0.f);

    int i = s0;
    for (; i + 7 < s1; i += 8) {
        uint4 cbA = *reinterpret_cast<const uint4*>(&colB[i]);
        uint4 cbB = *reinterpret_cast<const uint4*>(&colB[i + 4]);
        EDGE4(cbA);
        EDGE4(cbB);
    }
    if (i < s1) {   // remainder is exactly 4 (segments padded to x4)
        uint4 cb = *reinterpret_cast<const uint4*>(&colB[i]);
        EDGE4(cb);
    }

    float inv = 1.0f / s;
    const float4 bv = *reinterpret_cast<const float4*>(&b1[lane * 4]);
    float4 o;
    o.x = acc.x * inv + bv.x;
    o.y = acc.y * inv + bv.y;
    o.z = acc.z * inv + bv.z;
    o.w = acc.w * inv + bv.w;
    o.x = o.x > 0.f ? o.x : expm1f(o.x);
    o.y = o.y > 0.f ? o.y : expm1f(o.y);
    o.z = o.z > 0.f ? o.z : expm1f(o.z);
    o.w = o.w > 0.f ? o.w : expm1f(o.w);
    *reinterpret_cast<float4*>(&h1[(size_t)n * HIDC + lane * 4]) = o;
}

// ---------------- GEMM2 + fused att2 ----------------

__global__ __launch_bounds__(256) void gemm2_kernel(const float* __restrict__ X,
                                                    const float* __restrict__ W,
                                                    const float* __restrict__ a_src,
                                                    const float* __restrict__ a_dst,
                                                    float* __restrict__ Y,
                                                    float* __restrict__ ES2,
                                                    float* __restrict__ ED2, int N) {
    __shared__ float Ws[16][260];
    __shared__ float Xs[16][260];
    int tid = threadIdx.x;
    #pragma unroll
    for (int it = 0; it < 16; ++it) {
        int idx = tid + it * 256;
        int k = idx >> 4, c = idx & 15;
        Ws[c][k] = W[k * NCLS + c];
    }
    int row0 = blockIdx.x * 16;
    #pragma unroll
    for (int it = 0; it < 16; ++it) {
        int idx = tid + it * 256;
        int r = idx >> 8, k = idx & 255;
        int gr = row0 + r;
        Xs[r][k] = (gr < N) ? X[(size_t)gr * HIDC + k] : 0.f;
    }
    __syncthreads();
    int r = tid >> 4, c = tid & 15;
    float acc = 0.f;
    #pragma unroll 8
    for (int k = 0; k < 256; k += 4) {
        float4 xv = *reinterpret_cast<const float4*>(&Xs[r][k]);
        float4 wv = *reinterpret_cast<const float4*>(&Ws[c][k]);
        acc += xv.x * wv.x + xv.y * wv.y + xv.z * wv.z + xv.w * wv.w;
    }
    bool ok = (row0 + r) < N;
    if (ok) Y[(size_t)(row0 + r) * NCLS + c] = acc;
    // fused att2: reduce across the 16 c-lanes of each row
    float es = acc * a_src[c];
    float ed = acc * a_dst[c];
    #pragma unroll
    for (int off = 1; off < 16; off <<= 1) {
        es += __shfl_xor(es, off);
        ed += __shfl_xor(ed, off);
    }
    if (c == 0 && ok) {
        ES2[row0 + r] = es;
        ED2[row0 + r] = ed;
    }
}

// ---------------- Layer-2 aggregation + bias (4 nodes/block) ----------------

__global__ __launch_bounds__(256) void agg2_kernel(const float* __restrict__ H2,
                                                   const float* __restrict__ ES,
                                                   const float* __restrict__ ED,
                                                   const int* __restrict__ row_start,
                                                   const int* __restrict__ colB,
                                                   const float* __restrict__ b2,
                                                   float* __restrict__ out, int N) {
    int g = blockIdx.x * 4 + (threadIdx.x >> 6);
    if (g >= N) return;
    int lane = threadIdx.x & 63;
    int ep = lane >> 4;
    unsigned int c4 = (lane & 15) << 2;
    int s0 = row_start[g], s1 = row_start[g + 1];
    float ed = ED[g];
    const char* ESb = (const char*)ES;
    const char* H2b = (const char*)H2;
    float s = 0.f, acc = 0.f;
    for (int i = s0 + ep; i < s1; i += 4) {
        unsigned int cb = (unsigned int)colB[i];
        float e = *(const float*)(ESb + (cb >> 7));
        float hv = *(const float*)(H2b + ((cb >> 3) | c4));
        e += ed;
        e = fmaxf(e, NEG_SLOPE * e);
        float p = __expf(e);
        s += p;
        acc = fmaf(p, hv, acc);
    }
    s += __shfl_xor(s, 16);
    s += __shfl_xor(s, 32);
    acc += __shfl_xor(acc, 16);
    acc += __shfl_xor(acc, 32);
    if ((lane & 48) == 0) out[(size_t)g * NCLS + (lane & 15)] = acc / s + b2[lane & 15];
}

// ---------------- launch ----------------

extern "C" void kernel_launch(void* const* d_in, const int* in_sizes, int n_in,
                              void* d_out, int out_size, void* d_ws, size_t ws_size,
                              hipStream_t stream) {
    const float* x   = (const float*)d_in[0];
    const int*   ei  = (const int*)d_in[1];
    const float* W1  = (const float*)d_in[2];
    const float* as1 = (const float*)d_in[3];
    const float* ad1 = (const float*)d_in[4];
    const float* b1  = (const float*)d_in[5];
    const float* W2  = (const float*)d_in[6];
    const float* as2 = (const float*)d_in[7];
    const float* ad2 = (const float*)d_in[8];
    const float* b2  = (const float*)d_in[9];
    float* out = (float*)d_out;

    int N = in_sizes[0] / IN_CH;
    int E = in_sizes[1] / 2;
    int Etot = E + N;
    int fill_n = E + 4 * N;   // upper bound on padded CSR size

    char* ws = (char*)d_ws;
    size_t off = 0;
    auto alloc = [&](size_t bytes) -> void* {
        void* p = ws + off;
        off += (bytes + 255) & ~(size_t)255;
        return p;
    };
    unsigned short* Hb  = (unsigned short*)alloc((size_t)(N + 1) * HIDC * 2);
    unsigned short* W1t = (unsigned short*)alloc((size_t)HIDC * IN_CH * 2);
    float* h1  = (float*)alloc((size_t)N * HIDC * 4);
    float* H2  = (float*)alloc((size_t)(N + 1) * NCLS * 4);
    float* ES1 = (float*)alloc((size_t)(N + 1) * 8 * 4);
    float* ED1 = (float*)alloc((size_t)N * 8 * 4);
    float* ES2 = (float*)alloc((size_t)(N + 1) * 4);
    float* ED2 = (float*)alloc((size_t)N * 4);
    int* counts = (int*)alloc((size_t)N * 2 * 4);
    int* cursor = counts + N;
    int* row_start = (int*)alloc((size_t)(N + 1) * 4);
    int* colB = (int*)alloc((size_t)fill_n * 4);

    hipMemsetAsync(counts, 0, (size_t)N * 2 * 4, stream);

    int eb = (Etot + 255) / 256;
    count_fill_kernel<<<(fill_n + 255) / 256, 256, 0, stream>>>(
        ei, counts, E, Etot, colB, fill_n, N * HIDC * 2, Hb, ES1, H2, ES2, N);
    w1t_kernel<<<IN_CH, HIDC, 0, stream>>>(W1, W1t);
    scan_kernel<<<1, 1024, 0, stream>>>(counts, row_start, N);
    scatter_kernel<<<eb, 256, 0, stream>>>(ei, row_start, cursor, colB, E, Etot);

    dim3 g1((N + 127) / 128, 2);
    gemm1_mfma<<<g1, 256, 0, stream>>>(x, W1t, as1, ad1, Hb, ES1, ED1, N);
    agg1_kernel<<<(N + 3) / 4, 256, 0, stream>>>(Hb, ES1, ED1, row_start, colB, b1, h1, N);
    gemm2_kernel<<<(N + 15) / 16, 256, 0, stream>>>(h1, W2, as2, ad2, H2, ES2, ED2, N);
    agg2_kernel<<<(N + 3) / 4, 256, 0, stream>>>(H2, ES2, ED2, row_start, colB, b2, out, N);
}

// Round 10
// 332.724 us; speedup vs baseline: 1.7309x; 1.0658x over previous
//
#include <hip/hip_runtime.h>
#include <hip/hip_bf16.h>

// BiGAT: 2-layer GAT forward.
// N=50000, IN_CH=128, HID=32, HEADS=8, NCLS=16, E=800000 (+N self loops).
// R10: single-block scan replaced by 3-phase multi-block scan (scanA/B/C);
// w1t folded into count_fill. agg/gemm kernels unchanged from R9.

#define IN_CH 128
#define HIDC  256   // HEADS*HID
#define NCLS  16
#define NEG_SLOPE 0.2f

typedef short bf16x8 __attribute__((ext_vector_type(8)));
typedef float f32x4 __attribute__((ext_vector_type(4)));

__device__ __forceinline__ unsigned int f2bf(float f) {
    unsigned int u = __float_as_uint(f);
    return (u + 0x7fffu + ((u >> 16) & 1u)) >> 16;
}
__device__ __forceinline__ float bf_lo(unsigned int w) { return __uint_as_float(w << 16); }
__device__ __forceinline__ float bf_hi(unsigned int w) { return __uint_as_float(w & 0xffff0000u); }

// ---------------- CSR: count + colB/sentinel fill + W1 transpose (merged) ----------------

__global__ void count_fill_kernel(const int* __restrict__ ei, int* __restrict__ counts,
                                  int E, int Etot,
                                  int* __restrict__ colB, int fill_n, int dummyB,
                                  unsigned short* __restrict__ Hb, float* __restrict__ ES1,
                                  float* __restrict__ H2, float* __restrict__ ES2,
                                  const float* __restrict__ W1,
                                  unsigned short* __restrict__ W1t, int N) {
    int i = blockIdx.x * blockDim.x + threadIdx.x;
    if (i < Etot) {
        int dst = (i < E) ? ei[E + i] : (i - E);
        atomicAdd(&counts[dst], 1);
    }
    if (i < fill_n) colB[i] = dummyB;
    if (i < IN_CH * HIDC) {   // W1t[c][k] = bf16(W1[k][c])
        int c = i >> 7, k = i & 127;
        W1t[i] = (unsigned short)f2bf(W1[k * HIDC + c]);
    }
    if (i < HIDC) Hb[(size_t)N * HIDC + i] = 0;
    if (i < NCLS) H2[(size_t)N * NCLS + i] = 0.f;
    if (i < 8) ES1[(size_t)N * 8 + i] = -3.0e38f;
    if (i == 0) ES2[N] = -3.0e38f;
}

// ---------------- 3-phase exclusive scan over padded counts ((c+3)&~3) ----------------

// Phase A: block-local exclusive scan -> row_start; per-block total -> bsums
__global__ __launch_bounds__(256) void scanA_kernel(const int* __restrict__ counts,
                                                    int* __restrict__ row_start,
                                                    int* __restrict__ bsums, int n) {
    __shared__ int wsum[4];
    int tid = threadIdx.x, lane = tid & 63, wid = tid >> 6;
    int i = blockIdx.x * 256 + tid;
    int v = (i < n) ? ((counts[i] + 3) & ~3) : 0;
    int x = v;
    #pragma unroll
    for (int off = 1; off < 64; off <<= 1) {
        int t = __shfl_up(x, off);
        if (lane >= off) x += t;
    }
    if (lane == 63) wsum[wid] = x;
    __syncthreads();
    if (tid < 4) {
        int w = wsum[tid];
        #pragma unroll
        for (int off = 1; off < 4; off <<= 1) {
            int t = __shfl_up(w, off);
            if (tid >= off) w += t;
        }
        wsum[tid] = w;   // inclusive over waves
    }
    __syncthreads();
    int wex = wid ? wsum[wid - 1] : 0;
    if (i < n) row_start[i] = wex + (x - v);   // block-local exclusive
    if (tid == 255) bsums[blockIdx.x] = wsum[3];
}

// Phase B: scan the (<=256) block sums -> exclusive bofs; total -> row_start[n]
__global__ __launch_bounds__(256) void scanB_kernel(const int* __restrict__ bsums,
                                                    int* __restrict__ bofs,
                                                    int* __restrict__ row_start,
                                                    int nb, int n) {
    __shared__ int wsum[4];
    int tid = threadIdx.x, lane = tid & 63, wid = tid >> 6;
    int v = (tid < nb) ? bsums[tid] : 0;
    int x = v;
    #pragma unroll
    for (int off = 1; off < 64; off <<= 1) {
        int t = __shfl_up(x, off);
        if (lane >= off) x += t;
    }
    if (lane == 63) wsum[wid] = x;
    __syncthreads();
    if (tid < 4) {
        int w = wsum[tid];
        #pragma unroll
        for (int off = 1; off < 4; off <<= 1) {
            int t = __shfl_up(w, off);
            if (tid >= off) w += t;
        }
        wsum[tid] = w;
    }
    __syncthreads();
    int wex = wid ? wsum[wid - 1] : 0;
    if (tid < nb) bofs[tid] = wex + (x - v);
    if (tid == nb - 1) row_start[n] = wex + x;
}

// Phase C: add block offsets in place
__global__ __launch_bounds__(256) void scanC_kernel(int* __restrict__ row_start,
                                                    const int* __restrict__ bofs, int n) {
    int i = blockIdx.x * 256 + threadIdx.x;
    if (i < n) row_start[i] += bofs[blockIdx.x];
}

__global__ void scatter_kernel(const int* __restrict__ ei, const int* __restrict__ row_start,
                               int* __restrict__ cursor, int* __restrict__ colB,
                               int E, int Etot) {
    int e = blockIdx.x * blockDim.x + threadIdx.x;
    if (e >= Etot) return;
    int src, dst;
    if (e < E) { src = ei[e]; dst = ei[E + e]; }
    else       { src = e - E; dst = e - E; }
    int pos = row_start[dst] + atomicAdd(&cursor[dst], 1);
    colB[pos] = src * (HIDC * 2);   // byte offset of Hb row
}

// ---------------- GEMM1 (MFMA bf16) + fused att1 ----------------

#define LDK 72   // 64 k + 8 pad (bf16 elems)

__global__ __launch_bounds__(256) void gemm1_mfma(const float* __restrict__ A,
                                                  const unsigned short* __restrict__ W1t,
                                                  const float* __restrict__ a_src,
                                                  const float* __restrict__ a_dst,
                                                  unsigned short* __restrict__ Hb,
                                                  float* __restrict__ ES,
                                                  float* __restrict__ ED, int M) {
    __shared__ unsigned short As[128 * LDK];
    __shared__ unsigned short Bs[128 * LDK];
    int tid = threadIdx.x;
    int row0 = blockIdx.x * 128, col0 = blockIdx.y * 128;
    int lane = tid & 63, wid = tid >> 6;
    int wr = wid >> 1, wc = wid & 1;
    int la = lane & 15, lg = lane >> 4;
    f32x4 acc[4][4] = {};

    int r = tid >> 1, hf = tid & 1;
    int gr = row0 + r;
    bool okA = gr < M;
    const float4* asrc = reinterpret_cast<const float4*>(A + (size_t)(okA ? gr : 0) * IN_CH) + hf * 8;
    const uint4*  bsrc = reinterpret_cast<const uint4*>(W1t + (size_t)(col0 + r) * IN_CH) + hf * 4;
    unsigned short* adst = &As[r * LDK + hf * 32];
    unsigned short* bdst = &Bs[r * LDK + hf * 32];

    #pragma unroll
    for (int kt = 0; kt < 2; ++kt) {
        #pragma unroll
        for (int it = 0; it < 8; ++it) {
            float4 v = okA ? asrc[it] : make_float4(0.f, 0.f, 0.f, 0.f);
            uint2 w;
            w.x = f2bf(v.x) | (f2bf(v.y) << 16);
            w.y = f2bf(v.z) | (f2bf(v.w) << 16);
            *reinterpret_cast<uint2*>(adst + it * 4) = w;
        }
        #pragma unroll
        for (int it = 0; it < 4; ++it) {
            uint4 v = bsrc[it];
            *reinterpret_cast<uint4*>(bdst + it * 8) = v;
        }
        asrc += 16;
        bsrc += 8;
        __syncthreads();
        #pragma unroll
        for (int k0 = 0; k0 < 64; k0 += 32) {
            bf16x8 af[4], bfr[4];
            #pragma unroll
            for (int m = 0; m < 4; ++m)
                af[m] = *reinterpret_cast<const bf16x8*>(&As[(wr * 64 + m * 16 + la) * LDK + k0 + lg * 8]);
            #pragma unroll
            for (int n2 = 0; n2 < 4; ++n2)
                bfr[n2] = *reinterpret_cast<const bf16x8*>(&Bs[(wc * 64 + n2 * 16 + la) * LDK + k0 + lg * 8]);
            #pragma unroll
            for (int m = 0; m < 4; ++m) {
                #pragma unroll
                for (int n2 = 0; n2 < 4; ++n2)
                    acc[m][n2] = __builtin_amdgcn_mfma_f32_16x16x32_bf16(af[m], bfr[n2], acc[m][n2], 0, 0, 0);
            }
        }
        __syncthreads();
    }

    #pragma unroll
    for (int m = 0; m < 4; ++m) {
        #pragma unroll
        for (int j = 0; j < 4; ++j) {
            int grow = row0 + wr * 64 + m * 16 + lg * 4 + j;
            if (grow < M) {
                int gcol = col0 + wc * 64 + la;
                #pragma unroll
                for (int n2 = 0; n2 < 4; ++n2)
                    Hb[(size_t)grow * HIDC + gcol + n2 * 16] = (unsigned short)f2bf(acc[m][n2][j]);
            }
        }
    }

    // fused att1: wave covers heads h0,h0+1
    int h0 = (col0 + wc * 64) >> 5;
    float as00 = a_src[h0 * 32 + la],        as01 = a_src[h0 * 32 + 16 + la];
    float ad00 = a_dst[h0 * 32 + la],        ad01 = a_dst[h0 * 32 + 16 + la];
    float as10 = a_src[(h0 + 1) * 32 + la],  as11 = a_src[(h0 + 1) * 32 + 16 + la];
    float ad10 = a_dst[(h0 + 1) * 32 + la],  ad11 = a_dst[(h0 + 1) * 32 + 16 + la];
    #pragma unroll
    for (int m = 0; m < 4; ++m) {
        #pragma unroll
        for (int j = 0; j < 4; ++j) {
            float v0 = acc[m][0][j], v1 = acc[m][1][j];
            float v2 = acc[m][2][j], v3 = acc[m][3][j];
            float es0 = v0 * as00 + v1 * as01;
            float ed0 = v0 * ad00 + v1 * ad01;
            float es1 = v2 * as10 + v3 * as11;
            float ed1 = v2 * ad10 + v3 * ad11;
            #pragma unroll
            for (int off = 1; off < 16; off <<= 1) {
                es0 += __shfl_xor(es0, off);
                ed0 += __shfl_xor(ed0, off);
                es1 += __shfl_xor(es1, off);
                ed1 += __shfl_xor(ed1, off);
            }
            int grow = row0 + wr * 64 + m * 16 + lg * 4 + j;
            if (la == 0 && grow < M) {
                ES[grow * 8 + h0] = es0;
                ED[grow * 8 + h0] = ed0;
                ES[grow * 8 + h0 + 1] = es1;
                ED[grow * 8 + h0 + 1] = ed1;
            }
        }
    }
}

// ---------------- Layer-1 aggregation: 8-deep unroll ----------------

#define EDGE4(cbv)                                                              \
    {                                                                           \
        float e0 = *(const float*)(ESb + (((cbv).x >> 4) | hoff));              \
        float e1 = *(const float*)(ESb + (((cbv).y >> 4) | hoff));              \
        float e2 = *(const float*)(ESb + (((cbv).z >> 4) | hoff));              \
        float e3 = *(const float*)(ESb + (((cbv).w >> 4) | hoff));              \
        uint2 v0 = *(const uint2*)(Hbb + ((cbv).x + lane8));                    \
        uint2 v1 = *(const uint2*)(Hbb + ((cbv).y + lane8));                    \
        uint2 v2 = *(const uint2*)(Hbb + ((cbv).z + lane8));                    \
        uint2 v3 = *(const uint2*)(Hbb + ((cbv).w + lane8));                    \
        e0 += ed; e1 += ed; e2 += ed; e3 += ed;                                 \
        e0 = fmaxf(e0, NEG_SLOPE * e0);                                         \
        e1 = fmaxf(e1, NEG_SLOPE * e1);                                         \
        e2 = fmaxf(e2, NEG_SLOPE * e2);                                         \
        e3 = fmaxf(e3, NEG_SLOPE * e3);                                         \
        float p0 = __expf(e0), p1 = __expf(e1), p2 = __expf(e2), p3 = __expf(e3);\
        s += (p0 + p1) + (p2 + p3);                                             \
        acc.x = fmaf(p0, bf_lo(v0.x), acc.x);                                   \
        acc.y = fmaf(p0, bf_hi(v0.x), acc.y);                                   \
        acc.z = fmaf(p0, bf_lo(v0.y), acc.z);                                   \
        acc.w = fmaf(p0, bf_hi(v0.y), acc.w);                                   \
        acc.x = fmaf(p1, bf_lo(v1.x), acc.x);                                   \
        acc.y = fmaf(p1, bf_hi(v1.x), acc.y);                                   \
        acc.z = fmaf(p1, bf_lo(v1.y), acc.z);                                   \
        acc.w = fmaf(p1, bf_hi(v1.y), acc.w);                                   \
        acc.x = fmaf(p2, bf_lo(v2.x), acc.x);                                   \
        acc.y = fmaf(p2, bf_hi(v2.x), acc.y);                                   \
        acc.z = fmaf(p2, bf_lo(v2.y), acc.z);                                   \
        acc.w = fmaf(p2, bf_hi(v2.y), acc.w);                                   \
        acc.x = fmaf(p3, bf_lo(v3.x), acc.x);                                   \
        acc.y = fmaf(p3, bf_hi(v3.x), acc.y);                                   \
        acc.z = fmaf(p3, bf_lo(v3.y), acc.z);                                   \
        acc.w = fmaf(p3, bf_hi(v3.y), acc.w);                                   \
    }

__global__ __launch_bounds__(256) void agg1_kernel(const unsigned short* __restrict__ Hb,
                                                   const float* __restrict__ ES,
                                                   const float* __restrict__ ED,
                                                   const int* __restrict__ row_start,
                                                   const int* __restrict__ colB,
                                                   const float* __restrict__ b1,
                                                   float* __restrict__ h1, int N) {
    int n = blockIdx.x * 4 + (threadIdx.x >> 6);
    if (n >= N) return;
    int lane = threadIdx.x & 63;
    int h = lane >> 3;
    unsigned int hoff = h << 2;
    unsigned int lane8 = lane << 3;
    int s0 = row_start[n], s1 = row_start[n + 1];
    float ed = ED[n * 8 + h];
    const char* ESb = (const char*)ES;
    const char* Hbb = (const char*)Hb;

    float s = 0.f;
    float4 acc = make_float4(0.f, 0.f, 0.f, 0.f);

    int i = s0;
    for (; i + 7 < s1; i += 8) {
        uint4 cbA = *reinterpret_cast<const uint4*>(&colB[i]);
        uint4 cbB = *reinterpret_cast<const uint4*>(&colB[i + 4]);
        EDGE4(cbA);
        EDGE4(cbB);
    }
    if (i < s1) {
        uint4 cb = *reinterpret_cast<const uint4*>(&colB[i]);
        EDGE4(cb);
    }

    float inv = 1.0f / s;
    const float4 bv = *reinterpret_cast<const float4*>(&b1[lane * 4]);
    float4 o;
    o.x = acc.x * inv + bv.x;
    o.y = acc.y * inv + bv.y;
    o.z = acc.z * inv + bv.z;
    o.w = acc.w * inv + bv.w;
    o.x = o.x > 0.f ? o.x : expm1f(o.x);
    o.y = o.y > 0.f ? o.y : expm1f(o.y);
    o.z = o.z > 0.f ? o.z : expm1f(o.z);
    o.w = o.w > 0.f ? o.w : expm1f(o.w);
    *reinterpret_cast<float4*>(&h1[(size_t)n * HIDC + lane * 4]) = o;
}

// ---------------- GEMM2 + fused att2 ----------------

__global__ __launch_bounds__(256) void gemm2_kernel(const float* __restrict__ X,
                                                    const float* __restrict__ W,
                                                    const float* __restrict__ a_src,
                                                    const float* __restrict__ a_dst,
                                                    float* __restrict__ Y,
                                                    float* __restrict__ ES2,
                                                    float* __restrict__ ED2, int N) {
    __shared__ float Ws[16][260];
    __shared__ float Xs[16][260];
    int tid = threadIdx.x;
    #pragma unroll
    for (int it = 0; it < 16; ++it) {
        int idx = tid + it * 256;
        int k = idx >> 4, c = idx & 15;
        Ws[c][k] = W[k * NCLS + c];
    }
    int row0 = blockIdx.x * 16;
    #pragma unroll
    for (int it = 0; it < 16; ++it) {
        int idx = tid + it * 256;
        int r = idx >> 8, k = idx & 255;
        int gr = row0 + r;
        Xs[r][k] = (gr < N) ? X[(size_t)gr * HIDC + k] : 0.f;
    }
    __syncthreads();
    int r = tid >> 4, c = tid & 15;
    float acc = 0.f;
    #pragma unroll 8
    for (int k = 0; k < 256; k += 4) {
        float4 xv = *reinterpret_cast<const float4*>(&Xs[r][k]);
        float4 wv = *reinterpret_cast<const float4*>(&Ws[c][k]);
        acc += xv.x * wv.x + xv.y * wv.y + xv.z * wv.z + xv.w * wv.w;
    }
    bool ok = (row0 + r) < N;
    if (ok) Y[(size_t)(row0 + r) * NCLS + c] = acc;
    float es = acc * a_src[c];
    float ed = acc * a_dst[c];
    #pragma unroll
    for (int off = 1; off < 16; off <<= 1) {
        es += __shfl_xor(es, off);
        ed += __shfl_xor(ed, off);
    }
    if (c == 0 && ok) {
        ES2[row0 + r] = es;
        ED2[row0 + r] = ed;
    }
}

// ---------------- Layer-2 aggregation + bias (4 nodes/block) ----------------

__global__ __launch_bounds__(256) void agg2_kernel(const float* __restrict__ H2,
                                                   const float* __restrict__ ES,
                                                   const float* __restrict__ ED,
                                                   const int* __restrict__ row_start,
                                                   const int* __restrict__ colB,
                                                   const float* __restrict__ b2,
                                                   float* __restrict__ out, int N) {
    int g = blockIdx.x * 4 + (threadIdx.x >> 6);
    if (g >= N) return;
    int lane = threadIdx.x & 63;
    int ep = lane >> 4;
    unsigned int c4 = (lane & 15) << 2;
    int s0 = row_start[g], s1 = row_start[g + 1];
    float ed = ED[g];
    const char* ESb = (const char*)ES;
    const char* H2b = (const char*)H2;
    float s = 0.f, acc = 0.f;
    for (int i = s0 + ep; i < s1; i += 4) {
        unsigned int cb = (unsigned int)colB[i];
        float e = *(const float*)(ESb + (cb >> 7));
        float hv = *(const float*)(H2b + ((cb >> 3) | c4));
        e += ed;
        e = fmaxf(e, NEG_SLOPE * e);
        float p = __expf(e);
        s += p;
        acc = fmaf(p, hv, acc);
    }
    s += __shfl_xor(s, 16);
    s += __shfl_xor(s, 32);
    acc += __shfl_xor(acc, 16);
    acc += __shfl_xor(acc, 32);
    if ((lane & 48) == 0) out[(size_t)g * NCLS + (lane & 15)] = acc / s + b2[lane & 15];
}

// ---------------- launch ----------------

extern "C" void kernel_launch(void* const* d_in, const int* in_sizes, int n_in,
                              void* d_out, int out_size, void* d_ws, size_t ws_size,
                              hipStream_t stream) {
    const float* x   = (const float*)d_in[0];
    const int*   ei  = (const int*)d_in[1];
    const float* W1  = (const float*)d_in[2];
    const float* as1 = (const float*)d_in[3];
    const float* ad1 = (const float*)d_in[4];
    const float* b1  = (const float*)d_in[5];
    const float* W2  = (const float*)d_in[6];
    const float* as2 = (const float*)d_in[7];
    const float* ad2 = (const float*)d_in[8];
    const float* b2  = (const float*)d_in[9];
    float* out = (float*)d_out;

    int N = in_sizes[0] / IN_CH;
    int E = in_sizes[1] / 2;
    int Etot = E + N;
    int fill_n = E + 4 * N;   // upper bound on padded CSR size
    int nb = (N + 255) / 256; // scan blocks

    char* ws = (char*)d_ws;
    size_t off = 0;
    auto alloc = [&](size_t bytes) -> void* {
        void* p = ws + off;
        off += (bytes + 255) & ~(size_t)255;
        return p;
    };
    unsigned short* Hb  = (unsigned short*)alloc((size_t)(N + 1) * HIDC * 2);
    unsigned short* W1t = (unsigned short*)alloc((size_t)HIDC * IN_CH * 2);
    float* h1  = (float*)alloc((size_t)N * HIDC * 4);
    float* H2  = (float*)alloc((size_t)(N + 1) * NCLS * 4);
    float* ES1 = (float*)alloc((size_t)(N + 1) * 8 * 4);
    float* ED1 = (float*)alloc((size_t)N * 8 * 4);
    float* ES2 = (float*)alloc((size_t)(N + 1) * 4);
    float* ED2 = (float*)alloc((size_t)N * 4);
    int* counts = (int*)alloc((size_t)N * 2 * 4);
    int* cursor = counts + N;
    int* row_start = (int*)alloc((size_t)(N + 1) * 4);
    int* colB = (int*)alloc((size_t)fill_n * 4);
    int* bsums = (int*)alloc((size_t)256 * 4);
    int* bofs  = (int*)alloc((size_t)256 * 4);

    hipMemsetAsync(counts, 0, (size_t)N * 2 * 4, stream);

    int eb = (Etot + 255) / 256;
    count_fill_kernel<<<(fill_n + 255) / 256, 256, 0, stream>>>(
        ei, counts, E, Etot, colB, fill_n, N * HIDC * 2, Hb, ES1, H2, ES2, W1, W1t, N);
    scanA_kernel<<<nb, 256, 0, stream>>>(counts, row_start, bsums, N);
    scanB_kernel<<<1, 256, 0, stream>>>(bsums, bofs, row_start, nb, N);
    scanC_kernel<<<nb, 256, 0, stream>>>(row_start, bofs, N);
    scatter_kernel<<<eb, 256, 0, stream>>>(ei, row_start, cursor, colB, E, Etot);

    dim3 g1((N + 127) / 128, 2);
    gemm1_mfma<<<g1, 256, 0, stream>>>(x, W1t, as1, ad1, Hb, ES1, ED1, N);
    agg1_kernel<<<(N + 3) / 4, 256, 0, stream>>>(Hb, ES1, ED1, row_start, colB, b1, h1, N);
    gemm2_kernel<<<(N + 15) / 16, 256, 0, stream>>>(h1, W2, as2, ad2, H2, ES2, ED2, N);
    agg2_kernel<<<(N + 3) / 4, 256, 0, stream>>>(H2, ES2, ED2, row_start, colB, b2, out, N);
}

// Round 11
// 276.078 us; speedup vs baseline: 2.0860x; 1.2052x over previous
//
#include <hip/hip_runtime.h>
#include <hip/hip_bf16.h>

// BiGAT: 2-layer GAT forward.
// N=50000, IN_CH=128, HID=32, HEADS=8, NCLS=16, E=800000 (+N self loops).
// R11: gemm2+att2 fused INTO agg1 (h1 never materialized; wave computes its
// H2 row via LDS k-swizzled W2t + kg x col lane layout); scatter atomic-free
// (rank recorded in count pass); agg2 2x unroll.

#define IN_CH 128
#define HIDC  256   // HEADS*HID
#define NCLS  16
#define NEG_SLOPE 0.2f

typedef short bf16x8 __attribute__((ext_vector_type(8)));
typedef float f32x4 __attribute__((ext_vector_type(4)));

__device__ __forceinline__ unsigned int f2bf(float f) {
    unsigned int u = __float_as_uint(f);
    return (u + 0x7fffu + ((u >> 16) & 1u)) >> 16;
}
__device__ __forceinline__ float bf_lo(unsigned int w) { return __uint_as_float(w << 16); }
__device__ __forceinline__ float bf_hi(unsigned int w) { return __uint_as_float(w & 0xffff0000u); }

// ---------------- CSR: count(+rank) + colB/sentinel fill + W1 transpose ----------------

__global__ void count_fill_kernel(const int* __restrict__ ei, int* __restrict__ counts,
                                  int* __restrict__ erank, int E, int Etot,
                                  int* __restrict__ colB, int fill_n, int dummyB,
                                  unsigned short* __restrict__ Hb, float* __restrict__ ES1,
                                  float* __restrict__ H2, float* __restrict__ ES2,
                                  const float* __restrict__ W1,
                                  unsigned short* __restrict__ W1t, int N) {
    int i = blockIdx.x * blockDim.x + threadIdx.x;
    if (i < Etot) {
        int dst = (i < E) ? ei[E + i] : (i - E);
        erank[i] = atomicAdd(&counts[dst], 1);
    }
    if (i < fill_n) colB[i] = dummyB;
    if (i < IN_CH * HIDC) {   // W1t[c][k] = bf16(W1[k][c])
        int c = i >> 7, k = i & 127;
        W1t[i] = (unsigned short)f2bf(W1[k * HIDC + c]);
    }
    if (i < HIDC) Hb[(size_t)N * HIDC + i] = 0;
    if (i < NCLS) H2[(size_t)N * NCLS + i] = 0.f;
    if (i < 8) ES1[(size_t)N * 8 + i] = -3.0e38f;
    if (i == 0) ES2[N] = -3.0e38f;
}

// ---------------- 3-phase exclusive scan over padded counts ((c+3)&~3) ----------------

__global__ __launch_bounds__(256) void scanA_kernel(const int* __restrict__ counts,
                                                    int* __restrict__ row_start,
                                                    int* __restrict__ bsums, int n) {
    __shared__ int wsum[4];
    int tid = threadIdx.x, lane = tid & 63, wid = tid >> 6;
    int i = blockIdx.x * 256 + tid;
    int v = (i < n) ? ((counts[i] + 3) & ~3) : 0;
    int x = v;
    #pragma unroll
    for (int off = 1; off < 64; off <<= 1) {
        int t = __shfl_up(x, off);
        if (lane >= off) x += t;
    }
    if (lane == 63) wsum[wid] = x;
    __syncthreads();
    if (tid < 4) {
        int w = wsum[tid];
        #pragma unroll
        for (int off = 1; off < 4; off <<= 1) {
            int t = __shfl_up(w, off);
            if (tid >= off) w += t;
        }
        wsum[tid] = w;
    }
    __syncthreads();
    int wex = wid ? wsum[wid - 1] : 0;
    if (i < n) row_start[i] = wex + (x - v);
    if (tid == 255) bsums[blockIdx.x] = wsum[3];
}

__global__ __launch_bounds__(256) void scanB_kernel(const int* __restrict__ bsums,
                                                    int* __restrict__ bofs,
                                                    int* __restrict__ row_start,
                                                    int nb, int n) {
    __shared__ int wsum[4];
    int tid = threadIdx.x, lane = tid & 63, wid = tid >> 6;
    int v = (tid < nb) ? bsums[tid] : 0;
    int x = v;
    #pragma unroll
    for (int off = 1; off < 64; off <<= 1) {
        int t = __shfl_up(x, off);
        if (lane >= off) x += t;
    }
    if (lane == 63) wsum[wid] = x;
    __syncthreads();
    if (tid < 4) {
        int w = wsum[tid];
        #pragma unroll
        for (int off = 1; off < 4; off <<= 1) {
            int t = __shfl_up(w, off);
            if (tid >= off) w += t;
        }
        wsum[tid] = w;
    }
    __syncthreads();
    int wex = wid ? wsum[wid - 1] : 0;
    if (tid < nb) bofs[tid] = wex + (x - v);
    if (tid == nb - 1) row_start[n] = wex + x;
}

__global__ __launch_bounds__(256) void scanC_kernel(int* __restrict__ row_start,
                                                    const int* __restrict__ bofs, int n) {
    int i = blockIdx.x * 256 + threadIdx.x;
    if (i < n) row_start[i] += bofs[blockIdx.x];
}

// atomic-free scatter: pos = row_start[dst] + precomputed rank
__global__ void scatter_kernel(const int* __restrict__ ei, const int* __restrict__ row_start,
                               const int* __restrict__ erank, int* __restrict__ colB,
                               int E, int Etot) {
    int e = blockIdx.x * blockDim.x + threadIdx.x;
    if (e >= Etot) return;
    int src, dst;
    if (e < E) { src = ei[e]; dst = ei[E + e]; }
    else       { src = e - E; dst = e - E; }
    colB[row_start[dst] + erank[e]] = src * (HIDC * 2);
}

// ---------------- GEMM1 (MFMA bf16) + fused att1 ----------------

#define LDK 72   // 64 k + 8 pad (bf16 elems)

__global__ __launch_bounds__(256) void gemm1_mfma(const float* __restrict__ A,
                                                  const unsigned short* __restrict__ W1t,
                                                  const float* __restrict__ a_src,
                                                  const float* __restrict__ a_dst,
                                                  unsigned short* __restrict__ Hb,
                                                  float* __restrict__ ES,
                                                  float* __restrict__ ED, int M) {
    __shared__ unsigned short As[128 * LDK];
    __shared__ unsigned short Bs[128 * LDK];
    int tid = threadIdx.x;
    int row0 = blockIdx.x * 128, col0 = blockIdx.y * 128;
    int lane = tid & 63, wid = tid >> 6;
    int wr = wid >> 1, wc = wid & 1;
    int la = lane & 15, lg = lane >> 4;
    f32x4 acc[4][4] = {};

    int r = tid >> 1, hf = tid & 1;
    int gr = row0 + r;
    bool okA = gr < M;
    const float4* asrc = reinterpret_cast<const float4*>(A + (size_t)(okA ? gr : 0) * IN_CH) + hf * 8;
    const uint4*  bsrc = reinterpret_cast<const uint4*>(W1t + (size_t)(col0 + r) * IN_CH) + hf * 4;
    unsigned short* adst = &As[r * LDK + hf * 32];
    unsigned short* bdst = &Bs[r * LDK + hf * 32];

    #pragma unroll
    for (int kt = 0; kt < 2; ++kt) {
        #pragma unroll
        for (int it = 0; it < 8; ++it) {
            float4 v = okA ? asrc[it] : make_float4(0.f, 0.f, 0.f, 0.f);
            uint2 w;
            w.x = f2bf(v.x) | (f2bf(v.y) << 16);
            w.y = f2bf(v.z) | (f2bf(v.w) << 16);
            *reinterpret_cast<uint2*>(adst + it * 4) = w;
        }
        #pragma unroll
        for (int it = 0; it < 4; ++it) {
            uint4 v = bsrc[it];
            *reinterpret_cast<uint4*>(bdst + it * 8) = v;
        }
        asrc += 16;
        bsrc += 8;
        __syncthreads();
        #pragma unroll
        for (int k0 = 0; k0 < 64; k0 += 32) {
            bf16x8 af[4], bfr[4];
            #pragma unroll
            for (int m = 0; m < 4; ++m)
                af[m] = *reinterpret_cast<const bf16x8*>(&As[(wr * 64 + m * 16 + la) * LDK + k0 + lg * 8]);
            #pragma unroll
            for (int n2 = 0; n2 < 4; ++n2)
                bfr[n2] = *reinterpret_cast<const bf16x8*>(&Bs[(wc * 64 + n2 * 16 + la) * LDK + k0 + lg * 8]);
            #pragma unroll
            for (int m = 0; m < 4; ++m) {
                #pragma unroll
                for (int n2 = 0; n2 < 4; ++n2)
                    acc[m][n2] = __builtin_amdgcn_mfma_f32_16x16x32_bf16(af[m], bfr[n2], acc[m][n2], 0, 0, 0);
            }
        }
        __syncthreads();
    }

    #pragma unroll
    for (int m = 0; m < 4; ++m) {
        #pragma unroll
        for (int j = 0; j < 4; ++j) {
            int grow = row0 + wr * 64 + m * 16 + lg * 4 + j;
            if (grow < M) {
                int gcol = col0 + wc * 64 + la;
                #pragma unroll
                for (int n2 = 0; n2 < 4; ++n2)
                    Hb[(size_t)grow * HIDC + gcol + n2 * 16] = (unsigned short)f2bf(acc[m][n2][j]);
            }
        }
    }

    // fused att1: wave covers heads h0,h0+1
    int h0 = (col0 + wc * 64) >> 5;
    float as00 = a_src[h0 * 32 + la],        as01 = a_src[h0 * 32 + 16 + la];
    float ad00 = a_dst[h0 * 32 + la],        ad01 = a_dst[h0 * 32 + 16 + la];
    float as10 = a_src[(h0 + 1) * 32 + la],  as11 = a_src[(h0 + 1) * 32 + 16 + la];
    float ad10 = a_dst[(h0 + 1) * 32 + la],  ad11 = a_dst[(h0 + 1) * 32 + 16 + la];
    #pragma unroll
    for (int m = 0; m < 4; ++m) {
        #pragma unroll
        for (int j = 0; j < 4; ++j) {
            float v0 = acc[m][0][j], v1 = acc[m][1][j];
            float v2 = acc[m][2][j], v3 = acc[m][3][j];
            float es0 = v0 * as00 + v1 * as01;
            float ed0 = v0 * ad00 + v1 * ad01;
            float es1 = v2 * as10 + v3 * as11;
            float ed1 = v2 * ad10 + v3 * ad11;
            #pragma unroll
            for (int off = 1; off < 16; off <<= 1) {
                es0 += __shfl_xor(es0, off);
                ed0 += __shfl_xor(ed0, off);
                es1 += __shfl_xor(es1, off);
                ed1 += __shfl_xor(ed1, off);
            }
            int grow = row0 + wr * 64 + m * 16 + lg * 4 + j;
            if (la == 0 && grow < M) {
                ES[grow * 8 + h0] = es0;
                ED[grow * 8 + h0] = ed0;
                ES[grow * 8 + h0 + 1] = es1;
                ED[grow * 8 + h0 + 1] = ed1;
            }
        }
    }
}

// ---------------- agg1 + fused gemm2/att2 ----------------
// 4 nodes / 256-thread block; one wave per node. Edge loop as before; then the
// wave computes its H2 row (h1 . W2) via LDS with k-swizzle k+(k>>6).

#define EDGE4(cbv)                                                              \
    {                                                                           \
        float e0 = *(const float*)(ESb + (((cbv).x >> 4) | hoff));              \
        float e1 = *(const float*)(ESb + (((cbv).y >> 4) | hoff));              \
        float e2 = *(const float*)(ESb + (((cbv).z >> 4) | hoff));              \
        float e3 = *(const float*)(ESb + (((cbv).w >> 4) | hoff));              \
        uint2 v0 = *(const uint2*)(Hbb + ((cbv).x + lane8));                    \
        uint2 v1 = *(const uint2*)(Hbb + ((cbv).y + lane8));                    \
        uint2 v2 = *(const uint2*)(Hbb + ((cbv).z + lane8));                    \
        uint2 v3 = *(const uint2*)(Hbb + ((cbv).w + lane8));                    \
        e0 += ed; e1 += ed; e2 += ed; e3 += ed;                                 \
        e0 = fmaxf(e0, NEG_SLOPE * e0);                                         \
        e1 = fmaxf(e1, NEG_SLOPE * e1);                                         \
        e2 = fmaxf(e2, NEG_SLOPE * e2);                                         \
        e3 = fmaxf(e3, NEG_SLOPE * e3);                                         \
        float p0 = __expf(e0), p1 = __expf(e1), p2 = __expf(e2), p3 = __expf(e3);\
        s += (p0 + p1) + (p2 + p3);                                             \
        acc.x = fmaf(p0, bf_lo(v0.x), acc.x);                                   \
        acc.y = fmaf(p0, bf_hi(v0.x), acc.y);                                   \
        acc.z = fmaf(p0, bf_lo(v0.y), acc.z);                                   \
        acc.w = fmaf(p0, bf_hi(v0.y), acc.w);                                   \
        acc.x = fmaf(p1, bf_lo(v1.x), acc.x);                                   \
        acc.y = fmaf(p1, bf_hi(v1.x), acc.y);                                   \
        acc.z = fmaf(p1, bf_lo(v1.y), acc.z);                                   \
        acc.w = fmaf(p1, bf_hi(v1.y), acc.w);                                   \
        acc.x = fmaf(p2, bf_lo(v2.x), acc.x);                                   \
        acc.y = fmaf(p2, bf_hi(v2.x), acc.y);                                   \
        acc.z = fmaf(p2, bf_lo(v2.y), acc.z);                                   \
        acc.w = fmaf(p2, bf_hi(v2.y), acc.w);                                   \
        acc.x = fmaf(p3, bf_lo(v3.x), acc.x);                                   \
        acc.y = fmaf(p3, bf_hi(v3.x), acc.y);                                   \
        acc.z = fmaf(p3, bf_lo(v3.y), acc.z);                                   \
        acc.w = fmaf(p3, bf_hi(v3.y), acc.w);                                   \
    }

__global__ __launch_bounds__(256) void agg1_kernel(const unsigned short* __restrict__ Hb,
                                                   const float* __restrict__ ES,
                                                   const float* __restrict__ ED,
                                                   const int* __restrict__ row_start,
                                                   const int* __restrict__ colB,
                                                   const float* __restrict__ b1,
                                                   const float* __restrict__ W2,
                                                   const float* __restrict__ as2,
                                                   const float* __restrict__ ad2,
                                                   float* __restrict__ H2,
                                                   float* __restrict__ ES2,
                                                   float* __restrict__ ED2, int N) {
    __shared__ float W2t[16][260];   // W2t[c][k + (k>>6)]
    __shared__ float h1row[4][260];  // per-wave h1 row, same swizzle
    int tid = threadIdx.x;
    #pragma unroll
    for (int it = 0; it < 16; ++it) {
        int idx = tid + it * 256;      // idx = k*16 + c
        int c = idx & 15, k = idx >> 4;
        W2t[c][k + (k >> 6)] = W2[idx];
    }
    __syncthreads();

    int n = blockIdx.x * 4 + (tid >> 6);
    if (n >= N) return;
    int lane = tid & 63;
    int wv = tid >> 6;
    int h = lane >> 3;
    unsigned int hoff = h << 2;
    unsigned int lane8 = lane << 3;
    int s0 = row_start[n], s1 = row_start[n + 1];
    float ed = ED[n * 8 + h];
    const char* ESb = (const char*)ES;
    const char* Hbb = (const char*)Hb;

    float s = 0.f;
    float4 acc = make_float4(0.f, 0.f, 0.f, 0.f);

    int i = s0;
    for (; i + 7 < s1; i += 8) {
        uint4 cbA = *reinterpret_cast<const uint4*>(&colB[i]);
        uint4 cbB = *reinterpret_cast<const uint4*>(&colB[i + 4]);
        EDGE4(cbA);
        EDGE4(cbB);
    }
    if (i < s1) {
        uint4 cb = *reinterpret_cast<const uint4*>(&colB[i]);
        EDGE4(cb);
    }

    float inv = 1.0f / s;
    const float4 bv = *reinterpret_cast<const float4*>(&b1[lane * 4]);
    float4 o;
    o.x = acc.x * inv + bv.x;
    o.y = acc.y * inv + bv.y;
    o.z = acc.z * inv + bv.z;
    o.w = acc.w * inv + bv.w;
    o.x = o.x > 0.f ? o.x : expm1f(o.x);
    o.y = o.y > 0.f ? o.y : expm1f(o.y);
    o.z = o.z > 0.f ? o.z : expm1f(o.z);
    o.w = o.w > 0.f ? o.w : expm1f(o.w);

    // ---- fused gemm2: H2[n] = h1row . W2  (h1 never hits HBM) ----
    {
        float* hr = &h1row[wv][0];
        int base = lane * 4 + (lane >> 4);   // k + (k>>6), k = lane*4 (block of 4 never crosses 64)
        hr[base + 0] = o.x;
        hr[base + 1] = o.y;
        hr[base + 2] = o.z;
        hr[base + 3] = o.w;
        __builtin_amdgcn_wave_barrier();     // same-wave LDS RAW: pin order
        int kg = lane >> 4, c = lane & 15;
        const float* wcol = &W2t[c][kg * 65];
        const float* hseg = &hr[kg * 65];
        float p = 0.f;
        #pragma unroll 16
        for (int k = 0; k < 64; ++k) p = fmaf(hseg[k], wcol[k], p);
        p += __shfl_xor(p, 16);
        p += __shfl_xor(p, 32);              // all lanes with col c now hold H2[n][c]
        if (kg == 0) H2[(size_t)n * NCLS + c] = p;
        float es = p * as2[c];
        float edv = p * ad2[c];
        #pragma unroll
        for (int off = 1; off < 16; off <<= 1) {
            es += __shfl_xor(es, off);
            edv += __shfl_xor(edv, off);
        }
        if (lane == 0) {
            ES2[n] = es;
            ED2[n] = edv;
        }
    }
}

// ---------------- Layer-2 aggregation + bias (4 nodes/block, 2x unroll) ----------------

__global__ __launch_bounds__(256) void agg2_kernel(const float* __restrict__ H2,
                                                   const float* __restrict__ ES,
                                                   const float* __restrict__ ED,
                                                   const int* __restrict__ row_start,
                                                   const int* __restrict__ colB,
                                                   const float* __restrict__ b2,
                                                   float* __restrict__ out, int N) {
    int g = blockIdx.x * 4 + (threadIdx.x >> 6);
    if (g >= N) return;
    int lane = threadIdx.x & 63;
    int ep = lane >> 4;
    unsigned int c4 = (lane & 15) << 2;
    int s0 = row_start[g], s1 = row_start[g + 1];
    float ed = ED[g];
    const char* ESb = (const char*)ES;
    const char* H2b = (const char*)H2;
    float s = 0.f, acc = 0.f, sB = 0.f, accB = 0.f;
    int i = s0 + ep;
    for (; i + 4 < s1; i += 8) {
        unsigned int cb0 = (unsigned int)colB[i];
        unsigned int cb1 = (unsigned int)colB[i + 4];
        float e0 = *(const float*)(ESb + (cb0 >> 7));
        float e1 = *(const float*)(ESb + (cb1 >> 7));
        float hv0 = *(const float*)(H2b + ((cb0 >> 3) | c4));
        float hv1 = *(const float*)(H2b + ((cb1 >> 3) | c4));
        e0 += ed; e1 += ed;
        e0 = fmaxf(e0, NEG_SLOPE * e0);
        e1 = fmaxf(e1, NEG_SLOPE * e1);
        float p0 = __expf(e0), p1 = __expf(e1);
        s += p0; sB += p1;
        acc = fmaf(p0, hv0, acc);
        accB = fmaf(p1, hv1, accB);
    }
    if (i < s1) {
        unsigned int cb = (unsigned int)colB[i];
        float e = *(const float*)(ESb + (cb >> 7));
        float hv = *(const float*)(H2b + ((cb >> 3) | c4));
        e += ed;
        e = fmaxf(e, NEG_SLOPE * e);
        float p = __expf(e);
        s += p;
        acc = fmaf(p, hv, acc);
    }
    s += sB; acc += accB;
    s += __shfl_xor(s, 16);
    s += __shfl_xor(s, 32);
    acc += __shfl_xor(acc, 16);
    acc += __shfl_xor(acc, 32);
    if ((lane & 48) == 0) out[(size_t)g * NCLS + (lane & 15)] = acc / s + b2[lane & 15];
}

// ---------------- launch ----------------

extern "C" void kernel_launch(void* const* d_in, const int* in_sizes, int n_in,
                              void* d_out, int out_size, void* d_ws, size_t ws_size,
                              hipStream_t stream) {
    const float* x   = (const float*)d_in[0];
    const int*   ei  = (const int*)d_in[1];
    const float* W1  = (const float*)d_in[2];
    const float* as1 = (const float*)d_in[3];
    const float* ad1 = (const float*)d_in[4];
    const float* b1  = (const float*)d_in[5];
    const float* W2  = (const float*)d_in[6];
    const float* as2 = (const float*)d_in[7];
    const float* ad2 = (const float*)d_in[8];
    const float* b2  = (const float*)d_in[9];
    float* out = (float*)d_out;

    int N = in_sizes[0] / IN_CH;
    int E = in_sizes[1] / 2;
    int Etot = E + N;
    int fill_n = E + 4 * N;
    int nb = (N + 255) / 256;

    char* ws = (char*)d_ws;
    size_t off = 0;
    auto alloc = [&](size_t bytes) -> void* {
        void* p = ws + off;
        off += (bytes + 255) & ~(size_t)255;
        return p;
    };
    unsigned short* Hb  = (unsigned short*)alloc((size_t)(N + 1) * HIDC * 2);
    unsigned short* W1t = (unsigned short*)alloc((size_t)HIDC * IN_CH * 2);
    float* H2  = (float*)alloc((size_t)(N + 1) * NCLS * 4);
    float* ES1 = (float*)alloc((size_t)(N + 1) * 8 * 4);
    float* ED1 = (float*)alloc((size_t)N * 8 * 4);
    float* ES2 = (float*)alloc((size_t)(N + 1) * 4);
    float* ED2 = (float*)alloc((size_t)N * 4);
    int* counts = (int*)alloc((size_t)N * 4);
    int* erank  = (int*)alloc((size_t)Etot * 4);
    int* row_start = (int*)alloc((size_t)(N + 1) * 4);
    int* colB = (int*)alloc((size_t)fill_n * 4);
    int* bsums = (int*)alloc((size_t)256 * 4);
    int* bofs  = (int*)alloc((size_t)256 * 4);

    hipMemsetAsync(counts, 0, (size_t)N * 4, stream);

    int eb = (Etot + 255) / 256;
    count_fill_kernel<<<(fill_n + 255) / 256, 256, 0, stream>>>(
        ei, counts, erank, E, Etot, colB, fill_n, N * HIDC * 2, Hb, ES1, H2, ES2, W1, W1t, N);
    scanA_kernel<<<nb, 256, 0, stream>>>(counts, row_start, bsums, N);
    scanB_kernel<<<1, 256, 0, stream>>>(bsums, bofs, row_start, nb, N);
    scanC_kernel<<<nb, 256, 0, stream>>>(row_start, bofs, N);
    scatter_kernel<<<eb, 256, 0, stream>>>(ei, row_start, erank, colB, E, Etot);

    dim3 g1((N + 127) / 128, 2);
    gemm1_mfma<<<g1, 256, 0, stream>>>(x, W1t, as1, ad1, Hb, ES1, ED1, N);
    agg1_kernel<<<(N + 3) / 4, 256, 0, stream>>>(Hb, ES1, ED1, row_start, colB, b1,
                                                 W2, as2, ad2, H2, ES2, ED2, N);
    agg2_kernel<<<(N + 3) / 4, 256, 0, stream>>>(H2, ES2, ED2, row_start, colB, b2, out, N);
}